// Round 19
// baseline (329.045 us; speedup 1.0000x reference)
//
#include <hip/hip_runtime.h>
#include <hip/hip_bf16.h>

typedef float f32x4 __attribute__((ext_vector_type(4)));
typedef short s16x8 __attribute__((ext_vector_type(8)));
typedef short s16x4 __attribute__((ext_vector_type(4)));
typedef unsigned short u16;

#define HIDDEN 4096
#define NQ 32
#define NKV 8
#define HD 128
#define T_SEQ 2048
#define QKV_N ((NQ + 2 * NKV) * HD)   // 6144

__device__ __forceinline__ u16 f2bf(float f) {
    union { float f; unsigned u; } v; v.f = f;
    unsigned r = v.u + 0x7FFFu + ((v.u >> 16) & 1u);
    return (u16)(r >> 16);
}
__device__ __forceinline__ float b2f(u16 h) {
    union { unsigned u; float f; } v; v.u = ((unsigned)h) << 16; return v.f;
}
__device__ __forceinline__ void gload_lds16(const u16* g, u16* l) {
    __builtin_amdgcn_global_load_lds(
        (const __attribute__((address_space(1))) unsigned int*)g,
        (__attribute__((address_space(3))) unsigned int*)l,
        16, 0, 0);
}
// bijective XCD remap (nwg % 8 == 0): contiguous chunk per XCD
__device__ __forceinline__ int xcd_swz(int flat, int nwg) {
    return (flat & 7) * (nwg >> 3) + (flat >> 3);
}

// ---------------- f32 -> bf16 bulk convert (two segments) ----------------
__device__ __forceinline__ void conv8(const float* src, u16* dst, int i) {
    const float4 a = ((const float4*)src)[2 * i];
    const float4 b = ((const float4*)src)[2 * i + 1];
    s16x8 o;
    o[0] = (short)f2bf(a.x); o[1] = (short)f2bf(a.y);
    o[2] = (short)f2bf(a.z); o[3] = (short)f2bf(a.w);
    o[4] = (short)f2bf(b.x); o[5] = (short)f2bf(b.y);
    o[6] = (short)f2bf(b.z); o[7] = (short)f2bf(b.w);
    ((s16x8*)dst)[i] = o;
}
__global__ __launch_bounds__(256) void conv2_bf16_kern(
    const float* __restrict__ s1, u16* __restrict__ d1, int n1,
    const float* __restrict__ s2, u16* __restrict__ d2, int n2)
{
    for (int i = blockIdx.x * 256 + threadIdx.x; i < n1 + n2; i += gridDim.x * 256) {
        if (i < n1) conv8(s1, d1, i);
        else        conv8(s2, d2, i - n1);
    }
}

// ============ 8-phase GEMM: C[M,N] = A[M,K]*B[N,K]^T, tile 256 x (NI*64) ====
// r17-proven skeleton, templated. 512 thr = 8 waves (2M x 4N); per-wave out
// 128 x NI*16 (acc[8][NI]). Phases (mh,kh): 4*NI MFMA + <=(4+NI) ds_read;
// bq(kh) reused across mh. Chunk staging (64-row chunks, 1 gload/thread),
// slot-parity invariant (tile tau in slot tau&1):
//   ph1 -> A[s^1]{c1,c3}(t+1)   ph2 -> B[s^1]{c0..cNI-1}(t+1)
//   ph3 -> A[s]{c0,c2}(t+2)     ph4 -> no stage, vmcnt(2) (tails 0)
// Safety: A-mh0 (c0,c2) last read ph2 < stage ph3; A-mh1/B slot-s never
// staged during tile t. Swizzle: LDS[r][c]=glob[r][c^(r&7)], read c^(l15&7).
// gemm1: NI=3 (256x192, grid 32x8); gemm2: NI=2 (256x128, grid 32x8).
template<int NI, int OUT_BF16>
__global__ __launch_bounds__(512) void gemm_8ph(
    const u16* __restrict__ A, const u16* __restrict__ B,
    void* __restrict__ Cv, int N, int K)
{
    __shared__ u16 As[2][256 * 64];
    __shared__ u16 Bs[2][NI * 64 * 64];
    const int tid = threadIdx.x, lane = tid & 63, wid = tid >> 6;
    const int wr = wid >> 2, wc = wid & 3;
    const int lg = lane >> 4, l15 = lane & 15;
    const int m0 = blockIdx.y * 256, n0 = blockIdx.x * (NI * 64);
    const int nk = K >> 6;
    const int r8 = lane >> 3;
    const int csw = ((lane & 7) ^ r8) * 8;   // pre-swizzled source col (elems)

    f32x4 acc[8][NI] = {};
    s16x8 af[4], bq0[NI], bq1[NI];

    auto stageA = [&](int sl, int c, int kt) {
        gload_lds16(&A[(size_t)(m0 + c * 64 + wid * 8 + r8) * K + kt * 64 + csw],
                    &As[sl][(c * 64 + wid * 8) * 64]);
    };
    auto stageB = [&](int sl, int c, int kt) {
        gload_lds16(&B[(size_t)(n0 + c * 64 + wid * 8 + r8) * K + kt * 64 + csw],
                    &Bs[sl][(c * 64 + wid * 8) * 64]);
    };
    auto ldA = [&](int s_, int mh_, int kh_) {
#pragma unroll
        for (int mi = 0; mi < 4; ++mi)
            af[mi] = *(const s16x8*)&As[s_][
                ((wr * 128 + mh_ * 64 + mi * 16 + l15) << 6) +
                (((lg + kh_ * 4) ^ (l15 & 7)) << 3)];
    };
    auto ldB = [&](int s_, int kh_, s16x8 (&bq)[NI]) {
#pragma unroll
        for (int ni = 0; ni < NI; ++ni)
            bq[ni] = *(const s16x8*)&Bs[s_][
                ((wc * (NI * 16) + ni * 16 + l15) << 6) +
                (((lg + kh_ * 4) ^ (l15 & 7)) << 3)];
    };
    auto mm = [&](int mh_, s16x8 (&bq)[NI]) {
        __builtin_amdgcn_s_setprio(1);
#pragma unroll
        for (int mi = 0; mi < 4; ++mi)
#pragma unroll
            for (int ni = 0; ni < NI; ++ni)
                acc[mh_ * 4 + mi][ni] =
                    __builtin_amdgcn_mfma_f32_16x16x32_bf16(
                        af[mi], bq[ni], acc[mh_ * 4 + mi][ni], 0, 0, 0);
        __builtin_amdgcn_s_setprio(0);
    };
#define MIDSYNC                                               \
    asm volatile("" ::: "memory");                            \
    __builtin_amdgcn_s_barrier();                             \
    asm volatile("s_waitcnt lgkmcnt(0)" ::: "memory");        \
    __builtin_amdgcn_sched_barrier(0);

    // prologue: tile 0 full (4+NI loads) + tile 1 A-mh0 {c0,c2} (2 loads)
    stageA(0, 0, 0); stageA(0, 1, 0); stageA(0, 2, 0); stageA(0, 3, 0);
#pragma unroll
    for (int c = 0; c < NI; ++c) stageB(0, c, 0);
    stageA(1, 0, 1); stageA(1, 2, 1);
    asm volatile("s_waitcnt vmcnt(2)" ::: "memory");
    __builtin_amdgcn_s_barrier();

    for (int t = 0; t < nk; ++t) {
        const int s = t & 1;
        // ---- ph1 (mh0,kh0): stage A[s^1]{c1,c3}(t+1)
        ldA(s, 0, 0); ldB(s, 0, bq0);
        if (t + 1 < nk) { stageA(s ^ 1, 1, t + 1); stageA(s ^ 1, 3, t + 1); }
        MIDSYNC
        mm(0, bq0);
        __builtin_amdgcn_s_barrier();
        // ---- ph2 (mh0,kh1): stage B[s^1]{all}(t+1)
        ldA(s, 0, 1); ldB(s, 1, bq1);
        if (t + 1 < nk) {
#pragma unroll
            for (int c = 0; c < NI; ++c) stageB(s ^ 1, c, t + 1);
        }
        MIDSYNC
        mm(0, bq1);
        __builtin_amdgcn_s_barrier();
        // ---- ph3 (mh1,kh0): reuse bq0; stage A[s]{c0,c2}(t+2)
        ldA(s, 1, 0);
        if (t + 2 < nk) { stageA(s, 0, t + 2); stageA(s, 2, t + 2); }
        MIDSYNC
        mm(1, bq0);
        __builtin_amdgcn_s_barrier();
        // ---- ph4 (mh1,kh1): reuse bq1; counted vmcnt
        ldA(s, 1, 1);
        MIDSYNC
        mm(1, bq1);
        if (t + 2 < nk) asm volatile("s_waitcnt vmcnt(2)" ::: "memory");
        else            asm volatile("s_waitcnt vmcnt(0)" ::: "memory");
        asm volatile("" ::: "memory");
        __builtin_amdgcn_s_barrier();
    }
#undef MIDSYNC

#pragma unroll
    for (int mh = 0; mh < 2; ++mh)
#pragma unroll
    for (int mi = 0; mi < 4; ++mi)
#pragma unroll
    for (int ni = 0; ni < NI; ++ni) {
        int row0 = m0 + wr * 128 + mh * 64 + mi * 16 + lg * 4;
        int col  = n0 + wc * (NI * 16) + ni * 16 + l15;
#pragma unroll
        for (int r = 0; r < 4; ++r) {
            if (OUT_BF16)
                ((u16*)Cv)[(size_t)(row0 + r) * N + col] = f2bf(acc[mh * 4 + mi][ni][r]);
            else
                ((float*)Cv)[(size_t)(row0 + r) * N + col] = acc[mh * 4 + mi][ni][r];
        }
    }
}

// ---------------- Fused RMSNorm+RoPE and V-transpose ----------------
__global__ __launch_bounds__(256) void nr_vt_kern(
    const u16* __restrict__ qkv, const float* __restrict__ qw,
    const float* __restrict__ kw, u16* __restrict__ qr, u16* __restrict__ kr,
    u16* __restrict__ vt)
{
    __shared__ u16 Ts[128][66];
    const int id = blockIdx.x, tid = threadIdx.x;
    if (id < 20480) {
        const int t = id & 2047, h = (id >> 11) * 4 + (tid >> 6);
        const int i = tid & 63;
        const size_t rowbase = (size_t)t * QKV_N;
        const u16* src; const float* w; u16* dst;
        if (h < 32) {
            src = qkv + rowbase + h * HD; w = qw;
            dst = qr + ((size_t)h * T_SEQ + t) * HD;
        } else {
            int kh = h - 32;
            src = qkv + rowbase + NQ * HD + kh * HD; w = kw;
            dst = kr + ((size_t)kh * T_SEQ + t) * HD;
        }
        float x1 = b2f(src[i]), x2 = b2f(src[i + 64]);
        float ss = x1 * x1 + x2 * x2;
#pragma unroll
        for (int d = 32; d >= 1; d >>= 1) ss += __shfl_xor(ss, d);
        float rs = rsqrtf(ss * (1.0f / 128.0f) + 1e-6f);
        x1 *= rs * w[i];
        x2 *= rs * w[i + 64];
        float ang = (float)t * exp2f((float)i * -0.20762050593567985f);
        float sn, cs;
        sincosf(ang, &sn, &cs);
        dst[i]      = f2bf(x1 * cs - x2 * sn);
        dst[i + 64] = f2bf(x2 * cs + x1 * sn);
        return;
    }
    const int id2 = id - 20480;
    const int t0 = (id2 & 31) * 64, kh = id2 >> 5;
#pragma unroll
    for (int it = 0; it < 4; ++it) {
        int slot = tid + it * 256;
        int tl = slot >> 4, dc = (slot & 15) * 8;
        s16x8 v = *(const s16x8*)&qkv[(size_t)(t0 + tl) * QKV_N + (NQ + NKV) * HD + kh * HD + dc];
#pragma unroll
        for (int e = 0; e < 8; ++e) Ts[dc + e][tl] = (u16)v[e];
    }
    __syncthreads();
#pragma unroll
    for (int it = 0; it < 4; ++it) {
        int slot = tid + it * 256;
        int d = slot >> 3, c = (slot & 7) * 8;
        s16x8 v = *(const s16x8*)&Ts[d][c];
        *(s16x8*)&vt[((size_t)kh * HD + d) * T_SEQ + t0 + c] = v;
    }
}

// ---------------- Flash attention (causal, GQA), swapped-QK^T, QBLK=128 --------
#define KS(b, r, c) Ks[(b)][((r) << 7) + ((c) ^ (((r) & 7) << 3))]
#define VS(b, r, c) Vs[(b)][((r) << 6) + ((c) ^ (((r) & 7) << 3))]
#define PS(wv, r, c) Ps[((wv) << 10) + ((r) << 6) + ((c) ^ (((r) & 7) << 3))]

__global__ __launch_bounds__(512) void attn_kern(
    const u16* __restrict__ qr, const u16* __restrict__ kr,
    const u16* __restrict__ vt, u16* __restrict__ o,
    const float* __restrict__ wo, u16* __restrict__ wo_bf)
{
    __shared__ u16 Ks[2][64 * 128];
    __shared__ u16 Vs[2][128 * 64];
    __shared__ u16 Ps[8 * 16 * 64];
    const int tid = threadIdx.x, lane = tid & 63, w = tid >> 6;
    const int lg = lane >> 4, l15 = lane & 15;
    const int fb = (int)blockIdx.y * 8 + (int)blockIdx.x;
    const int flat = xcd_swz(fb, 256);
    const int qh = flat >> 3, bx = flat & 7;
    const int kvh = qh >> 2;
    const float scale2 = 0.08838834764831845f * 1.4426950408889634f;

    const int cvbase = fb * 8192 + tid;
    int cv = 0;
    float4 cva = {}, cvb = {};

    const int krow = tid >> 4, kcol = (tid & 15) * 8;
    const int vrow = tid >> 3, vcol = (tid & 7) * 8;
    const u16* krbase = kr + (size_t)kvh * T_SEQ * HD;
    const u16* vtbase = vt + (size_t)kvh * HD * T_SEQ;

    s16x8 kst[2], vst[2];
#define LOADKV(k0_) do { \
    kst[0] = *(const s16x8*)&krbase[(size_t)((k0_) + krow) * HD + kcol]; \
    kst[1] = *(const s16x8*)&krbase[(size_t)((k0_) + krow + 32) * HD + kcol]; \
    vst[0] = *(const s16x8*)&vtbase[(size_t)(vrow) * T_SEQ + (k0_) + vcol]; \
    vst[1] = *(const s16x8*)&vtbase[(size_t)(vrow + 64) * T_SEQ + (k0_) + vcol]; \
    } while (0)
#define WRITEKV(b) do { \
    *(s16x8*)&KS((b), krow, kcol) = kst[0]; \
    *(s16x8*)&KS((b), krow + 32, kcol) = kst[1]; \
    *(s16x8*)&VS((b), vrow, vcol) = vst[0]; \
    *(s16x8*)&VS((b), vrow + 64, vcol) = vst[1]; \
    } while (0)

    for (int half = 0; half < 2; ++half) {
        const int q0 = (half == 0) ? bx * 128 : (T_SEQ - 128) - bx * 128;
        s16x8 qf[4];
        {
            const u16* qb = qr + ((size_t)qh * T_SEQ + q0 + w * 16 + l15) * HD;
#pragma unroll
            for (int dc = 0; dc < 4; ++dc) qf[dc] = *(const s16x8*)&qb[dc * 32 + lg * 8];
        }
        f32x4 oacc[8] = {};
        float mQ = -1e30f, lsQ = 0.f;

        const int ktiles = (q0 >> 6) + 2;
        LOADKV(0);
        WRITEKV(0);
        __syncthreads();
        for (int kt = 0; kt < ktiles; ++kt) {
            const int k0 = kt * 64;
            const int cur = kt & 1;
            if (kt + 1 < ktiles) LOADKV(k0 + 64);

            if (cv <= 16) {
                if (cv > 0) {
                    s16x8 o8;
                    o8[0] = (short)f2bf(cva.x); o8[1] = (short)f2bf(cva.y);
                    o8[2] = (short)f2bf(cva.z); o8[3] = (short)f2bf(cva.w);
                    o8[4] = (short)f2bf(cvb.x); o8[5] = (short)f2bf(cvb.y);
                    o8[6] = (short)f2bf(cvb.z); o8[7] = (short)f2bf(cvb.w);
                    ((s16x8*)wo_bf)[cvbase + (cv - 1) * 512] = o8;
                }
                if (cv < 16) {
                    cva = ((const float4*)wo)[2 * (cvbase + cv * 512)];
                    cvb = ((const float4*)wo)[2 * (cvbase + cv * 512) + 1];
                }
                ++cv;
            }

            f32x4 sc[4] = {};
            __builtin_amdgcn_s_setprio(1);
#pragma unroll
            for (int nc = 0; nc < 4; ++nc)
#pragma unroll
                for (int dc = 0; dc < 4; ++dc) {
                    s16x8 kf = *(const s16x8*)&KS(cur, nc * 16 + l15, dc * 32 + lg * 8);
                    sc[nc] = __builtin_amdgcn_mfma_f32_16x16x32_bf16(kf, qf[dc], sc[nc], 0, 0, 0);
                }
            __builtin_amdgcn_s_setprio(0);

            const int qg = q0 + w * 16 + l15;
            const bool needMask = (k0 + 63) > (q0 + w * 16);
            float tm = -1e30f;
#pragma unroll
            for (int nc = 0; nc < 4; ++nc)
#pragma unroll
                for (int r = 0; r < 4; ++r) {
                    float v = sc[nc][r] * scale2;
                    int kg = k0 + nc * 16 + lg * 4 + r;
                    if (needMask && kg > qg) v = -1e30f;
                    sc[nc][r] = v;
                    tm = fmaxf(tm, v);
                }
            tm = fmaxf(tm, __shfl_xor(tm, 16));
            tm = fmaxf(tm, __shfl_xor(tm, 32));

            if (__any(tm > mQ + 8.0f)) {
                float mn = fmaxf(mQ, tm);
                float alpha = exp2f(mQ - mn);
                mQ = mn;
                lsQ *= alpha;
                float aq[4];
#pragma unroll
                for (int r = 0; r < 4; ++r) aq[r] = __shfl(alpha, lg * 4 + r);
#pragma unroll
                for (int dc = 0; dc < 8; ++dc)
#pragma unroll
                    for (int r = 0; r < 4; ++r) oacc[dc][r] *= aq[r];
            }

            float ts = 0.f;
#pragma unroll
            for (int nc = 0; nc < 4; ++nc) {
                s16x4 pk;
#pragma unroll
                for (int r = 0; r < 4; ++r) {
                    float e = exp2f(sc[nc][r] - mQ);
                    ts += e;
                    pk[r] = (short)f2bf(e);
                }
                *(s16x4*)&PS(w, l15, nc * 16 + lg * 4) = pk;
            }
            ts += __shfl_xor(ts, 16);
            ts += __shfl_xor(ts, 32);
            lsQ += ts;

            __builtin_amdgcn_s_setprio(1);
#pragma unroll
            for (int kc = 0; kc < 2; ++kc) {
                s16x8 pf = *(const s16x8*)&PS(w, l15, kc * 32 + lg * 8);
#pragma unroll
                for (int dc = 0; dc < 8; ++dc) {
                    s16x8 vf = *(const s16x8*)&VS(cur, dc * 16 + l15, kc * 32 + lg * 8);
                    oacc[dc] = __builtin_amdgcn_mfma_f32_16x16x32_bf16(pf, vf, oacc[dc], 0, 0, 0);
                }
            }
            __builtin_amdgcn_s_setprio(0);

            if (kt + 1 < ktiles) WRITEKV(cur ^ 1);
            __syncthreads();
        }
        float lq[4];
#pragma unroll
        for (int r = 0; r < 4; ++r) lq[r] = __shfl(lsQ, lg * 4 + r);
#pragma unroll
        for (int r = 0; r < 4; ++r) {
            float inv = 1.0f / lq[r];
            int trow = q0 + w * 16 + lg * 4 + r;
            u16* dst = o + (size_t)trow * (NQ * HD) + qh * HD;
#pragma unroll
            for (int dc = 0; dc < 8; ++dc) dst[dc * 16 + l15] = f2bf(oacc[dc][r] * inv);
        }
    }
#undef LOADKV
#undef WRITEKV
}

extern "C" void kernel_launch(void* const* d_in, const int* in_sizes, int n_in,
                              void* d_out, int out_size, void* d_ws, size_t ws_size,
                              hipStream_t stream)
{
    const float* hs   = (const float*)d_in[0];
    const float* wqkv = (const float*)d_in[1];
    const float* qw   = (const float*)d_in[2];
    const float* kw   = (const float*)d_in[3];
    const float* wo   = (const float*)d_in[4];
    float* out = (float*)d_out;

    // workspace 92,274,688 B (88 MiB). Fully disjoint live regions per stage
    // (fixes r14-r18 overlap bug: wqkv_bf [40,88M) vs qkv_bf [64,88M)):
    //   gemm1: R hs_bf[0,16M) + wqkv_bf[40,88M)  -> W qkv_bf[16,40M)
    //   nr_vt: R qkv_bf[16,40M)                  -> W qr[64,80M) kr[80,84M) vt[84,88M)
    //   attn : R qr/kr/vt[64,88M) + wo(input)    -> W ob[0,16M) + wo_bf[16,48M)
    //   gemm2: R ob[0,16M) + wo_bf[16,48M)       -> W d_out
    char* ws = (char*)d_ws;
    u16* hs_bf   = (u16*)(ws);                  // [0,16M)
    u16* ob      = (u16*)(ws);                  // [0,16M)  (after gemm1)
    u16* qkv_bf  = (u16*)(ws + 16777216);       // [16,40M)
    u16* wo_bf   = (u16*)(ws + 16777216);       // [16,48M) (after nr_vt)
    u16* wqkv_bf = (u16*)(ws + 41943040);       // [40,88M)
    u16* qr      = (u16*)(ws + 67108864);       // [64,80M)
    u16* kr      = (u16*)(ws + 83886080);       // [80,84M)
    u16* vt      = (u16*)(ws + 88080384);       // [84,88M)

    // 1) convert hs + wqkv
    conv2_bf16_kern<<<2048, 256, 0, stream>>>(
        hs, hs_bf, T_SEQ * HIDDEN / 8, wqkv, wqkv_bf, QKV_N * HIDDEN / 8);
    // 2) qkv = hs @ wqkv^T  (256x192 8-phase, 256 blocks = 1/CU)
    gemm_8ph<3, 1><<<dim3(QKV_N / 192, T_SEQ / 256), 512, 0, stream>>>(
        hs_bf, wqkv_bf, (void*)qkv_bf, QKV_N, HIDDEN);
    // 3) fused norm+rope / V-transpose (last reader of qkv_bf)
    nr_vt_kern<<<20736, 256, 0, stream>>>(qkv_bf, qw, kw, qr, kr, vt);
    // 4) attention with embedded wo conversion
    attn_kern<<<dim3(8, NQ), 512, 0, stream>>>(qr, kr, vt, ob, wo, wo_bf);
    // 5) out = o @ wo^T  (256x128 8-phase, 256 blocks = 1/CU)
    gemm_8ph<2, 0><<<dim3(HIDDEN / 128, T_SEQ / 256), 512, 0, stream>>>(
        ob, wo_bf, (void*)out, HIDDEN, HIDDEN);
}

// Round 20
// 322.348 us; speedup vs baseline: 1.0208x; 1.0208x over previous
//
#include <hip/hip_runtime.h>
#include <hip/hip_bf16.h>

typedef float f32x4 __attribute__((ext_vector_type(4)));
typedef short s16x8 __attribute__((ext_vector_type(8)));
typedef short s16x4 __attribute__((ext_vector_type(4)));
typedef unsigned short u16;

#define HIDDEN 4096
#define NQ 32
#define NKV 8
#define HD 128
#define T_SEQ 2048
#define QKV_N ((NQ + 2 * NKV) * HD)   // 6144

__device__ __forceinline__ u16 f2bf(float f) {
    union { float f; unsigned u; } v; v.f = f;
    unsigned r = v.u + 0x7FFFu + ((v.u >> 16) & 1u);
    return (u16)(r >> 16);
}
__device__ __forceinline__ float b2f(u16 h) {
    union { unsigned u; float f; } v; v.u = ((unsigned)h) << 16; return v.f;
}
__device__ __forceinline__ void gload_lds16(const u16* g, u16* l) {
    __builtin_amdgcn_global_load_lds(
        (const __attribute__((address_space(1))) unsigned int*)g,
        (__attribute__((address_space(3))) unsigned int*)l,
        16, 0, 0);
}
// bijective XCD remap (nwg % 8 == 0): contiguous chunk per XCD
__device__ __forceinline__ int xcd_swz(int flat, int nwg) {
    return (flat & 7) * (nwg >> 3) + (flat >> 3);
}

// ---------------- f32 -> bf16 bulk convert (two segments) ----------------
__device__ __forceinline__ void conv8(const float* src, u16* dst, int i) {
    const float4 a = ((const float4*)src)[2 * i];
    const float4 b = ((const float4*)src)[2 * i + 1];
    s16x8 o;
    o[0] = (short)f2bf(a.x); o[1] = (short)f2bf(a.y);
    o[2] = (short)f2bf(a.z); o[3] = (short)f2bf(a.w);
    o[4] = (short)f2bf(b.x); o[5] = (short)f2bf(b.y);
    o[6] = (short)f2bf(b.z); o[7] = (short)f2bf(b.w);
    ((s16x8*)dst)[i] = o;
}
__global__ __launch_bounds__(256) void conv2_bf16_kern(
    const float* __restrict__ s1, u16* __restrict__ d1, int n1,
    const float* __restrict__ s2, u16* __restrict__ d2, int n2)
{
    for (int i = blockIdx.x * 256 + threadIdx.x; i < n1 + n2; i += gridDim.x * 256) {
        if (i < n1) conv8(s1, d1, i);
        else        conv8(s2, d2, i - n1);
    }
}

// ============ gemm1: 256x192 tile, BK=64, 8-phase counted-vmcnt (r17) =======
// 256-block grid (32x8) = 1 block/CU. 512 thr = 8 waves (2M x 4N); per-wave
// out 128x48 (acc[8][3]). Phases (mh,kh): 12 MFMA + <=7 ds_read; bq(kh)
// reused across mh. Chunk staging (64-row chunks), slot-parity invariant:
//   ph1 -> A[s^1]{c1,c3}(t+1)   ph2 -> B[s^1]{c0,c1,c2}(t+1)
//   ph3 -> A[s]{c0,c2}(t+2)     ph4 -> no stage, vmcnt(2) (tails 0)
__global__ __launch_bounds__(512) void gemm1_8ph(
    const u16* __restrict__ A, const u16* __restrict__ B,
    u16* __restrict__ C, int N, int K)
{
    __shared__ u16 As[2][256 * 64];
    __shared__ u16 Bs[2][192 * 64];
    const int tid = threadIdx.x, lane = tid & 63, wid = tid >> 6;
    const int wr = wid >> 2, wc = wid & 3;
    const int lg = lane >> 4, l15 = lane & 15;
    const int m0 = blockIdx.y * 256, n0 = blockIdx.x * 192;
    const int nk = K >> 6;
    const int r8 = lane >> 3;
    const int csw = ((lane & 7) ^ r8) * 8;

    f32x4 acc[8][3] = {};
    s16x8 af[4], bq0[3], bq1[3];

    auto stageA = [&](int sl, int c, int kt) {
        gload_lds16(&A[(size_t)(m0 + c * 64 + wid * 8 + r8) * K + kt * 64 + csw],
                    &As[sl][(c * 64 + wid * 8) * 64]);
    };
    auto stageB = [&](int sl, int c, int kt) {
        gload_lds16(&B[(size_t)(n0 + c * 64 + wid * 8 + r8) * K + kt * 64 + csw],
                    &Bs[sl][(c * 64 + wid * 8) * 64]);
    };
    auto ldA = [&](int s_, int mh_, int kh_) {
#pragma unroll
        for (int mi = 0; mi < 4; ++mi)
            af[mi] = *(const s16x8*)&As[s_][
                ((wr * 128 + mh_ * 64 + mi * 16 + l15) << 6) +
                (((lg + kh_ * 4) ^ (l15 & 7)) << 3)];
    };
    auto ldB = [&](int s_, int kh_, s16x8 (&bq)[3]) {
#pragma unroll
        for (int ni = 0; ni < 3; ++ni)
            bq[ni] = *(const s16x8*)&Bs[s_][
                ((wc * 48 + ni * 16 + l15) << 6) +
                (((lg + kh_ * 4) ^ (l15 & 7)) << 3)];
    };
    auto mm = [&](int mh_, s16x8 (&bq)[3]) {
        __builtin_amdgcn_s_setprio(1);
#pragma unroll
        for (int mi = 0; mi < 4; ++mi)
#pragma unroll
            for (int ni = 0; ni < 3; ++ni)
                acc[mh_ * 4 + mi][ni] =
                    __builtin_amdgcn_mfma_f32_16x16x32_bf16(
                        af[mi], bq[ni], acc[mh_ * 4 + mi][ni], 0, 0, 0);
        __builtin_amdgcn_s_setprio(0);
    };
#define MIDSYNC                                               \
    asm volatile("" ::: "memory");                            \
    __builtin_amdgcn_s_barrier();                             \
    asm volatile("s_waitcnt lgkmcnt(0)" ::: "memory");        \
    __builtin_amdgcn_sched_barrier(0);

    stageA(0, 0, 0); stageA(0, 1, 0); stageA(0, 2, 0); stageA(0, 3, 0);
    stageB(0, 0, 0); stageB(0, 1, 0); stageB(0, 2, 0);
    stageA(1, 0, 1); stageA(1, 2, 1);
    asm volatile("s_waitcnt vmcnt(2)" ::: "memory");
    __builtin_amdgcn_s_barrier();

    for (int t = 0; t < nk; ++t) {
        const int s = t & 1;
        ldA(s, 0, 0); ldB(s, 0, bq0);
        if (t + 1 < nk) { stageA(s ^ 1, 1, t + 1); stageA(s ^ 1, 3, t + 1); }
        MIDSYNC
        mm(0, bq0);
        __builtin_amdgcn_s_barrier();
        ldA(s, 0, 1); ldB(s, 1, bq1);
        if (t + 1 < nk) { stageB(s ^ 1, 0, t + 1); stageB(s ^ 1, 1, t + 1); stageB(s ^ 1, 2, t + 1); }
        MIDSYNC
        mm(0, bq1);
        __builtin_amdgcn_s_barrier();
        ldA(s, 1, 0);
        if (t + 2 < nk) { stageA(s, 0, t + 2); stageA(s, 2, t + 2); }
        MIDSYNC
        mm(1, bq0);
        __builtin_amdgcn_s_barrier();
        ldA(s, 1, 1);
        MIDSYNC
        mm(1, bq1);
        if (t + 2 < nk) asm volatile("s_waitcnt vmcnt(2)" ::: "memory");
        else            asm volatile("s_waitcnt vmcnt(0)" ::: "memory");
        asm volatile("" ::: "memory");
        __builtin_amdgcn_s_barrier();
    }
#undef MIDSYNC

#pragma unroll
    for (int mh = 0; mh < 2; ++mh)
#pragma unroll
    for (int mi = 0; mi < 4; ++mi)
#pragma unroll
    for (int ni = 0; ni < 3; ++ni) {
        int row0 = m0 + wr * 128 + mh * 64 + mi * 16 + lg * 4;
        int col  = n0 + wc * 48 + ni * 16 + l15;
#pragma unroll
        for (int r = 0; r < 4; ++r)
            C[(size_t)(row0 + r) * N + col] = f2bf(acc[mh * 4 + mi][ni][r]);
    }
}

// ---------------- GEMM (128² 2-phase, proven): C = A * B^T ----------------
// gemm2: 512 blocks = 2/CU; NI=2 8-phase was ~90us (thin phases), this is 83.
template<int OUT_BF16>
__global__ __launch_bounds__(256) void gemm_bt_bf16(
    const u16* __restrict__ A, const u16* __restrict__ B,
    void* __restrict__ Cv, int N, int K)
{
    __shared__ u16 As[2][128 * 32];
    __shared__ u16 Bs[2][128 * 32];
    const int tid = threadIdx.x, lane = tid & 63, wid = tid >> 6;
    const int wr = wid >> 1, wc = wid & 1, lg = lane >> 4, l15 = lane & 15;
    const int m0 = blockIdx.y * 128, n0 = blockIdx.x * 128;
    const int srow = wid * 32 + (lane >> 2);
    const int scol = (((lane & 3) ^ ((lane >> 3) & 3))) * 8;
    const u16* ga = &A[(size_t)(m0 + srow) * K + scol];
    const u16* gb = &B[(size_t)(n0 + srow) * K + scol];
    const int rsw = (lg ^ ((l15 >> 1) & 3)) * 8;

    f32x4 acc[4][4] = {};
    const int nk = K >> 5;

    auto stage = [&](int buf, int koff) {
        u16* la = &As[buf][wid * 1024];
        u16* lb = &Bs[buf][wid * 1024];
        gload_lds16(ga + koff, la);
        gload_lds16(ga + koff + 16 * K, la + 512);
        gload_lds16(gb + koff, lb);
        gload_lds16(gb + koff + 16 * K, lb + 512);
    };

    stage(0, 0);
    for (int kk = 0; kk < nk; ++kk) {
        const int cur = kk & 1;
        if (kk + 1 < nk) {
            stage(cur ^ 1, (kk + 1) * 32);
            asm volatile("s_waitcnt vmcnt(4)" ::: "memory");
        } else {
            asm volatile("s_waitcnt vmcnt(0)" ::: "memory");
        }
        __builtin_amdgcn_s_barrier();
        s16x8 af[4], bfr[4];
#pragma unroll
        for (int i = 0; i < 4; ++i) af[i]  = *(const s16x8*)&As[cur][(wr * 64 + i * 16 + l15) * 32 + rsw];
#pragma unroll
        for (int j = 0; j < 4; ++j) bfr[j] = *(const s16x8*)&Bs[cur][(wc * 64 + j * 16 + l15) * 32 + rsw];
#pragma unroll
        for (int i = 0; i < 4; ++i)
#pragma unroll
            for (int j = 0; j < 4; ++j)
                acc[i][j] = __builtin_amdgcn_mfma_f32_16x16x32_bf16(af[i], bfr[j], acc[i][j], 0, 0, 0);
        __builtin_amdgcn_s_barrier();
    }
#pragma unroll
    for (int i = 0; i < 4; ++i) {
        int r0 = m0 + wr * 64 + i * 16 + lg * 4;
#pragma unroll
        for (int j = 0; j < 4; ++j) {
            int cc = n0 + wc * 64 + j * 16 + l15;
#pragma unroll
            for (int r = 0; r < 4; ++r) {
                if (OUT_BF16)
                    ((u16*)Cv)[(size_t)(r0 + r) * N + cc] = f2bf(acc[i][j][r]);
                else
                    ((float*)Cv)[(size_t)(r0 + r) * N + cc] = acc[i][j][r];
            }
        }
    }
}

// ---------------- Fused RMSNorm+RoPE and V-transpose ----------------
__global__ __launch_bounds__(256) void nr_vt_kern(
    const u16* __restrict__ qkv, const float* __restrict__ qw,
    const float* __restrict__ kw, u16* __restrict__ qr, u16* __restrict__ kr,
    u16* __restrict__ vt)
{
    __shared__ u16 Ts[128][66];
    const int id = blockIdx.x, tid = threadIdx.x;
    if (id < 20480) {
        const int t = id & 2047, h = (id >> 11) * 4 + (tid >> 6);
        const int i = tid & 63;
        const size_t rowbase = (size_t)t * QKV_N;
        const u16* src; const float* w; u16* dst;
        if (h < 32) {
            src = qkv + rowbase + h * HD; w = qw;
            dst = qr + ((size_t)h * T_SEQ + t) * HD;
        } else {
            int kh = h - 32;
            src = qkv + rowbase + NQ * HD + kh * HD; w = kw;
            dst = kr + ((size_t)kh * T_SEQ + t) * HD;
        }
        float x1 = b2f(src[i]), x2 = b2f(src[i + 64]);
        float ss = x1 * x1 + x2 * x2;
#pragma unroll
        for (int d = 32; d >= 1; d >>= 1) ss += __shfl_xor(ss, d);
        float rs = rsqrtf(ss * (1.0f / 128.0f) + 1e-6f);
        x1 *= rs * w[i];
        x2 *= rs * w[i + 64];
        float ang = (float)t * exp2f((float)i * -0.20762050593567985f);
        float sn, cs;
        sincosf(ang, &sn, &cs);
        dst[i]      = f2bf(x1 * cs - x2 * sn);
        dst[i + 64] = f2bf(x2 * cs + x1 * sn);
        return;
    }
    const int id2 = id - 20480;
    const int t0 = (id2 & 31) * 64, kh = id2 >> 5;
#pragma unroll
    for (int it = 0; it < 4; ++it) {
        int slot = tid + it * 256;
        int tl = slot >> 4, dc = (slot & 15) * 8;
        s16x8 v = *(const s16x8*)&qkv[(size_t)(t0 + tl) * QKV_N + (NQ + NKV) * HD + kh * HD + dc];
#pragma unroll
        for (int e = 0; e < 8; ++e) Ts[dc + e][tl] = (u16)v[e];
    }
    __syncthreads();
#pragma unroll
    for (int it = 0; it < 4; ++it) {
        int slot = tid + it * 256;
        int d = slot >> 3, c = (slot & 7) * 8;
        s16x8 v = *(const s16x8*)&Ts[d][c];
        *(s16x8*)&vt[((size_t)kh * HD + d) * T_SEQ + t0 + c] = v;
    }
}

// ---------------- Flash attention (causal, GQA), swapped-QK^T, QBLK=128 --------
#define KS(b, r, c) Ks[(b)][((r) << 7) + ((c) ^ (((r) & 7) << 3))]
#define VS(b, r, c) Vs[(b)][((r) << 6) + ((c) ^ (((r) & 7) << 3))]
#define PS(wv, r, c) Ps[((wv) << 10) + ((r) << 6) + ((c) ^ (((r) & 7) << 3))]

__global__ __launch_bounds__(512) void attn_kern(
    const u16* __restrict__ qr, const u16* __restrict__ kr,
    const u16* __restrict__ vt, u16* __restrict__ o,
    const float* __restrict__ wo, u16* __restrict__ wo_bf)
{
    __shared__ u16 Ks[2][64 * 128];
    __shared__ u16 Vs[2][128 * 64];
    __shared__ u16 Ps[8 * 16 * 64];
    const int tid = threadIdx.x, lane = tid & 63, w = tid >> 6;
    const int lg = lane >> 4, l15 = lane & 15;
    const int fb = (int)blockIdx.y * 8 + (int)blockIdx.x;
    const int flat = xcd_swz(fb, 256);
    const int qh = flat >> 3, bx = flat & 7;
    const int kvh = qh >> 2;
    const float scale2 = 0.08838834764831845f * 1.4426950408889634f;

    const int cvbase = fb * 8192 + tid;
    int cv = 0;
    float4 cva = {}, cvb = {};

    const int krow = tid >> 4, kcol = (tid & 15) * 8;
    const int vrow = tid >> 3, vcol = (tid & 7) * 8;
    const u16* krbase = kr + (size_t)kvh * T_SEQ * HD;
    const u16* vtbase = vt + (size_t)kvh * HD * T_SEQ;

    s16x8 kst[2], vst[2];
#define LOADKV(k0_) do { \
    kst[0] = *(const s16x8*)&krbase[(size_t)((k0_) + krow) * HD + kcol]; \
    kst[1] = *(const s16x8*)&krbase[(size_t)((k0_) + krow + 32) * HD + kcol]; \
    vst[0] = *(const s16x8*)&vtbase[(size_t)(vrow) * T_SEQ + (k0_) + vcol]; \
    vst[1] = *(const s16x8*)&vtbase[(size_t)(vrow + 64) * T_SEQ + (k0_) + vcol]; \
    } while (0)
#define WRITEKV(b) do { \
    *(s16x8*)&KS((b), krow, kcol) = kst[0]; \
    *(s16x8*)&KS((b), krow + 32, kcol) = kst[1]; \
    *(s16x8*)&VS((b), vrow, vcol) = vst[0]; \
    *(s16x8*)&VS((b), vrow + 64, vcol) = vst[1]; \
    } while (0)

    for (int half = 0; half < 2; ++half) {
        const int q0 = (half == 0) ? bx * 128 : (T_SEQ - 128) - bx * 128;
        s16x8 qf[4];
        {
            const u16* qb = qr + ((size_t)qh * T_SEQ + q0 + w * 16 + l15) * HD;
#pragma unroll
            for (int dc = 0; dc < 4; ++dc) qf[dc] = *(const s16x8*)&qb[dc * 32 + lg * 8];
        }
        f32x4 oacc[8] = {};
        float mQ = -1e30f, lsQ = 0.f;

        const int ktiles = (q0 >> 6) + 2;
        LOADKV(0);
        WRITEKV(0);
        __syncthreads();
        for (int kt = 0; kt < ktiles; ++kt) {
            const int k0 = kt * 64;
            const int cur = kt & 1;
            if (kt + 1 < ktiles) LOADKV(k0 + 64);

            if (cv <= 16) {
                if (cv > 0) {
                    s16x8 o8;
                    o8[0] = (short)f2bf(cva.x); o8[1] = (short)f2bf(cva.y);
                    o8[2] = (short)f2bf(cva.z); o8[3] = (short)f2bf(cva.w);
                    o8[4] = (short)f2bf(cvb.x); o8[5] = (short)f2bf(cvb.y);
                    o8[6] = (short)f2bf(cvb.z); o8[7] = (short)f2bf(cvb.w);
                    ((s16x8*)wo_bf)[cvbase + (cv - 1) * 512] = o8;
                }
                if (cv < 16) {
                    cva = ((const float4*)wo)[2 * (cvbase + cv * 512)];
                    cvb = ((const float4*)wo)[2 * (cvbase + cv * 512) + 1];
                }
                ++cv;
            }

            f32x4 sc[4] = {};
            __builtin_amdgcn_s_setprio(1);
#pragma unroll
            for (int nc = 0; nc < 4; ++nc)
#pragma unroll
                for (int dc = 0; dc < 4; ++dc) {
                    s16x8 kf = *(const s16x8*)&KS(cur, nc * 16 + l15, dc * 32 + lg * 8);
                    sc[nc] = __builtin_amdgcn_mfma_f32_16x16x32_bf16(kf, qf[dc], sc[nc], 0, 0, 0);
                }
            __builtin_amdgcn_s_setprio(0);

            const int qg = q0 + w * 16 + l15;
            const bool needMask = (k0 + 63) > (q0 + w * 16);
            float tm = -1e30f;
#pragma unroll
            for (int nc = 0; nc < 4; ++nc)
#pragma unroll
                for (int r = 0; r < 4; ++r) {
                    float v = sc[nc][r] * scale2;
                    int kg = k0 + nc * 16 + lg * 4 + r;
                    if (needMask && kg > qg) v = -1e30f;
                    sc[nc][r] = v;
                    tm = fmaxf(tm, v);
                }
            tm = fmaxf(tm, __shfl_xor(tm, 16));
            tm = fmaxf(tm, __shfl_xor(tm, 32));

            if (__any(tm > mQ + 8.0f)) {
                float mn = fmaxf(mQ, tm);
                float alpha = exp2f(mQ - mn);
                mQ = mn;
                lsQ *= alpha;
                float aq[4];
#pragma unroll
                for (int r = 0; r < 4; ++r) aq[r] = __shfl(alpha, lg * 4 + r);
#pragma unroll
                for (int dc = 0; dc < 8; ++dc)
#pragma unroll
                    for (int r = 0; r < 4; ++r) oacc[dc][r] *= aq[r];
            }

            float ts = 0.f;
#pragma unroll
            for (int nc = 0; nc < 4; ++nc) {
                s16x4 pk;
#pragma unroll
                for (int r = 0; r < 4; ++r) {
                    float e = exp2f(sc[nc][r] - mQ);
                    ts += e;
                    pk[r] = (short)f2bf(e);
                }
                *(s16x4*)&PS(w, l15, nc * 16 + lg * 4) = pk;
            }
            ts += __shfl_xor(ts, 16);
            ts += __shfl_xor(ts, 32);
            lsQ += ts;

            __builtin_amdgcn_s_setprio(1);
#pragma unroll
            for (int kc = 0; kc < 2; ++kc) {
                s16x8 pf = *(const s16x8*)&PS(w, l15, kc * 32 + lg * 8);
#pragma unroll
                for (int dc = 0; dc < 8; ++dc) {
                    s16x8 vf = *(const s16x8*)&VS(cur, dc * 16 + l15, kc * 32 + lg * 8);
                    oacc[dc] = __builtin_amdgcn_mfma_f32_16x16x32_bf16(pf, vf, oacc[dc], 0, 0, 0);
                }
            }
            __builtin_amdgcn_s_setprio(0);

            if (kt + 1 < ktiles) WRITEKV(cur ^ 1);
            __syncthreads();
        }
        float lq[4];
#pragma unroll
        for (int r = 0; r < 4; ++r) lq[r] = __shfl(lsQ, lg * 4 + r);
#pragma unroll
        for (int r = 0; r < 4; ++r) {
            float inv = 1.0f / lq[r];
            int trow = q0 + w * 16 + lg * 4 + r;
            u16* dst = o + (size_t)trow * (NQ * HD) + qh * HD;
#pragma unroll
            for (int dc = 0; dc < 8; ++dc) dst[dc * 16 + l15] = f2bf(oacc[dc][r] * inv);
        }
    }
#undef LOADKV
#undef WRITEKV
}

extern "C" void kernel_launch(void* const* d_in, const int* in_sizes, int n_in,
                              void* d_out, int out_size, void* d_ws, size_t ws_size,
                              hipStream_t stream)
{
    const float* hs   = (const float*)d_in[0];
    const float* wqkv = (const float*)d_in[1];
    const float* qw   = (const float*)d_in[2];
    const float* kw   = (const float*)d_in[3];
    const float* wo   = (const float*)d_in[4];
    float* out = (float*)d_out;

    // workspace 92,274,688 B (88 MiB). Fully disjoint live regions per stage:
    //   gemm1: R hs_bf[0,16M) + wqkv_bf[40,88M)  -> W qkv_bf[16,40M)
    //   nr_vt: R qkv_bf[16,40M)                  -> W qr[64,80M) kr[80,84M) vt[84,88M)
    //   attn : R qr/kr/vt[64,88M) + wo(input)    -> W ob[0,16M) + wo_bf[16,48M)
    //   gemm2: R ob[0,16M) + wo_bf[16,48M)       -> W d_out
    char* ws = (char*)d_ws;
    u16* hs_bf   = (u16*)(ws);                  // [0,16M)
    u16* ob      = (u16*)(ws);                  // [0,16M)  (after gemm1)
    u16* qkv_bf  = (u16*)(ws + 16777216);       // [16,40M)
    u16* wo_bf   = (u16*)(ws + 16777216);       // [16,48M) (after nr_vt)
    u16* wqkv_bf = (u16*)(ws + 41943040);       // [40,88M)
    u16* qr      = (u16*)(ws + 67108864);       // [64,80M)
    u16* kr      = (u16*)(ws + 83886080);       // [80,84M)
    u16* vt      = (u16*)(ws + 88080384);       // [84,88M)

    // 1) convert hs + wqkv
    conv2_bf16_kern<<<2048, 256, 0, stream>>>(
        hs, hs_bf, T_SEQ * HIDDEN / 8, wqkv, wqkv_bf, QKV_N * HIDDEN / 8);
    // 2) qkv = hs @ wqkv^T  (256x192 8-phase, 256 blocks = 1/CU)
    gemm1_8ph<<<dim3(QKV_N / 192, T_SEQ / 256), 512, 0, stream>>>(
        hs_bf, wqkv_bf, qkv_bf, QKV_N, HIDDEN);
    // 3) fused norm+rope / V-transpose (last reader of qkv_bf)
    nr_vt_kern<<<20736, 256, 0, stream>>>(qkv_bf, qw, kw, qr, kr, vt);
    // 4) attention with embedded wo conversion
    attn_kern<<<dim3(8, NQ), 512, 0, stream>>>(qr, kr, vt, ob, wo, wo_bf);
    // 5) out = o @ wo^T  (128² 2-phase, 512 blocks = 2/CU; NI=2 8-phase was ~90us)
    gemm_bt_bf16<0><<<dim3(HIDDEN / 128, T_SEQ / 128), 256, 0, stream>>>(
        ob, wo_bf, (void*)out, HIDDEN, HIDDEN);
}

// Round 21
// 321.858 us; speedup vs baseline: 1.0223x; 1.0015x over previous
//
#include <hip/hip_runtime.h>
#include <hip/hip_bf16.h>

typedef float f32x4 __attribute__((ext_vector_type(4)));
typedef short s16x8 __attribute__((ext_vector_type(8)));
typedef short s16x4 __attribute__((ext_vector_type(4)));
typedef unsigned short u16;

#define HIDDEN 4096
#define NQ 32
#define NKV 8
#define HD 128
#define T_SEQ 2048
#define QKV_N ((NQ + 2 * NKV) * HD)   // 6144

__device__ __forceinline__ u16 f2bf(float f) {
    union { float f; unsigned u; } v; v.f = f;
    unsigned r = v.u + 0x7FFFu + ((v.u >> 16) & 1u);
    return (u16)(r >> 16);
}
__device__ __forceinline__ float b2f(u16 h) {
    union { unsigned u; float f; } v; v.u = ((unsigned)h) << 16; return v.f;
}
__device__ __forceinline__ void gload_lds16(const u16* g, u16* l) {
    __builtin_amdgcn_global_load_lds(
        (const __attribute__((address_space(1))) unsigned int*)g,
        (__attribute__((address_space(3))) unsigned int*)l,
        16, 0, 0);
}
// bijective XCD remap (nwg % 8 == 0): contiguous chunk per XCD
__device__ __forceinline__ int xcd_swz(int flat, int nwg) {
    return (flat & 7) * (nwg >> 3) + (flat >> 3);
}

// ---------------- f32 -> bf16 bulk convert (two segments) ----------------
__device__ __forceinline__ void conv8(const float* src, u16* dst, int i) {
    const float4 a = ((const float4*)src)[2 * i];
    const float4 b = ((const float4*)src)[2 * i + 1];
    s16x8 o;
    o[0] = (short)f2bf(a.x); o[1] = (short)f2bf(a.y);
    o[2] = (short)f2bf(a.z); o[3] = (short)f2bf(a.w);
    o[4] = (short)f2bf(b.x); o[5] = (short)f2bf(b.y);
    o[6] = (short)f2bf(b.z); o[7] = (short)f2bf(b.w);
    ((s16x8*)dst)[i] = o;
}
__global__ __launch_bounds__(256) void conv2_bf16_kern(
    const float* __restrict__ s1, u16* __restrict__ d1, int n1,
    const float* __restrict__ s2, u16* __restrict__ d2, int n2)
{
    for (int i = blockIdx.x * 256 + threadIdx.x; i < n1 + n2; i += gridDim.x * 256) {
        if (i < n1) conv8(s1, d1, i);
        else        conv8(s2, d2, i - n1);
    }
}

// ============ gemm1: 256x192 tile, BK=64, 8-phase counted-vmcnt (r17) =======
// 256-block grid (32x8) = 1 block/CU. 512 thr = 8 waves (2M x 4N); per-wave
// out 128x48 (acc[8][3]). Phases (mh,kh): 12 MFMA + <=7 ds_read; bq(kh)
// reused across mh. Chunk staging (64-row chunks), slot-parity invariant:
//   ph1 -> A[s^1]{c1,c3}(t+1)   ph2 -> B[s^1]{c0,c1,c2}(t+1)
//   ph3 -> A[s]{c0,c2}(t+2)     ph4 -> no stage, vmcnt(2) (tails 0)
// r21: MIDSYNC drops lgkmcnt(0)+sched_barrier(0) — ds_reads are plain C++
// loads, so the compiler emits fine-grained lgkmcnt(N) before each dependent
// MFMA (early MFMAs overlap late reads). Safety: every read is consumed by an
// MFMA in its own phase, so all reads complete before the trailing barrier,
// hence before any later-phase stage overwrites the region. Compiler fences
// pin loads within their phase.
__global__ __launch_bounds__(512) void gemm1_8ph(
    const u16* __restrict__ A, const u16* __restrict__ B,
    u16* __restrict__ C, int N, int K)
{
    __shared__ u16 As[2][256 * 64];
    __shared__ u16 Bs[2][192 * 64];
    const int tid = threadIdx.x, lane = tid & 63, wid = tid >> 6;
    const int wr = wid >> 2, wc = wid & 3;
    const int lg = lane >> 4, l15 = lane & 15;
    const int m0 = blockIdx.y * 256, n0 = blockIdx.x * 192;
    const int nk = K >> 6;
    const int r8 = lane >> 3;
    const int csw = ((lane & 7) ^ r8) * 8;

    f32x4 acc[8][3] = {};
    s16x8 af[4], bq0[3], bq1[3];

    auto stageA = [&](int sl, int c, int kt) {
        gload_lds16(&A[(size_t)(m0 + c * 64 + wid * 8 + r8) * K + kt * 64 + csw],
                    &As[sl][(c * 64 + wid * 8) * 64]);
    };
    auto stageB = [&](int sl, int c, int kt) {
        gload_lds16(&B[(size_t)(n0 + c * 64 + wid * 8 + r8) * K + kt * 64 + csw],
                    &Bs[sl][(c * 64 + wid * 8) * 64]);
    };
    auto ldA = [&](int s_, int mh_, int kh_) {
#pragma unroll
        for (int mi = 0; mi < 4; ++mi)
            af[mi] = *(const s16x8*)&As[s_][
                ((wr * 128 + mh_ * 64 + mi * 16 + l15) << 6) +
                (((lg + kh_ * 4) ^ (l15 & 7)) << 3)];
    };
    auto ldB = [&](int s_, int kh_, s16x8 (&bq)[3]) {
#pragma unroll
        for (int ni = 0; ni < 3; ++ni)
            bq[ni] = *(const s16x8*)&Bs[s_][
                ((wc * 48 + ni * 16 + l15) << 6) +
                (((lg + kh_ * 4) ^ (l15 & 7)) << 3)];
    };
    auto mm = [&](int mh_, s16x8 (&bq)[3]) {
        __builtin_amdgcn_s_setprio(1);
#pragma unroll
        for (int mi = 0; mi < 4; ++mi)
#pragma unroll
            for (int ni = 0; ni < 3; ++ni)
                acc[mh_ * 4 + mi][ni] =
                    __builtin_amdgcn_mfma_f32_16x16x32_bf16(
                        af[mi], bq[ni], acc[mh_ * 4 + mi][ni], 0, 0, 0);
        __builtin_amdgcn_s_setprio(0);
    };
#define MIDSYNC                                               \
    asm volatile("" ::: "memory");                            \
    __builtin_amdgcn_s_barrier();

    stageA(0, 0, 0); stageA(0, 1, 0); stageA(0, 2, 0); stageA(0, 3, 0);
    stageB(0, 0, 0); stageB(0, 1, 0); stageB(0, 2, 0);
    stageA(1, 0, 1); stageA(1, 2, 1);
    asm volatile("s_waitcnt vmcnt(2)" ::: "memory");
    __builtin_amdgcn_s_barrier();

    for (int t = 0; t < nk; ++t) {
        const int s = t & 1;
        ldA(s, 0, 0); ldB(s, 0, bq0);
        if (t + 1 < nk) { stageA(s ^ 1, 1, t + 1); stageA(s ^ 1, 3, t + 1); }
        MIDSYNC
        mm(0, bq0);
        __builtin_amdgcn_s_barrier();
        ldA(s, 0, 1); ldB(s, 1, bq1);
        if (t + 1 < nk) { stageB(s ^ 1, 0, t + 1); stageB(s ^ 1, 1, t + 1); stageB(s ^ 1, 2, t + 1); }
        MIDSYNC
        mm(0, bq1);
        __builtin_amdgcn_s_barrier();
        ldA(s, 1, 0);
        if (t + 2 < nk) { stageA(s, 0, t + 2); stageA(s, 2, t + 2); }
        MIDSYNC
        mm(1, bq0);
        __builtin_amdgcn_s_barrier();
        ldA(s, 1, 1);
        MIDSYNC
        mm(1, bq1);
        if (t + 2 < nk) asm volatile("s_waitcnt vmcnt(2)" ::: "memory");
        else            asm volatile("s_waitcnt vmcnt(0)" ::: "memory");
        asm volatile("" ::: "memory");
        __builtin_amdgcn_s_barrier();
    }
#undef MIDSYNC

#pragma unroll
    for (int mh = 0; mh < 2; ++mh)
#pragma unroll
    for (int mi = 0; mi < 4; ++mi)
#pragma unroll
    for (int ni = 0; ni < 3; ++ni) {
        int row0 = m0 + wr * 128 + mh * 64 + mi * 16 + lg * 4;
        int col  = n0 + wc * 48 + ni * 16 + l15;
#pragma unroll
        for (int r = 0; r < 4; ++r)
            C[(size_t)(row0 + r) * N + col] = f2bf(acc[mh * 4 + mi][ni][r]);
    }
}

// ---------------- GEMM (128² 2-phase, proven): C = A * B^T ----------------
template<int OUT_BF16>
__global__ __launch_bounds__(256) void gemm_bt_bf16(
    const u16* __restrict__ A, const u16* __restrict__ B,
    void* __restrict__ Cv, int N, int K)
{
    __shared__ u16 As[2][128 * 32];
    __shared__ u16 Bs[2][128 * 32];
    const int tid = threadIdx.x, lane = tid & 63, wid = tid >> 6;
    const int wr = wid >> 1, wc = wid & 1, lg = lane >> 4, l15 = lane & 15;
    const int m0 = blockIdx.y * 128, n0 = blockIdx.x * 128;
    const int srow = wid * 32 + (lane >> 2);
    const int scol = (((lane & 3) ^ ((lane >> 3) & 3))) * 8;
    const u16* ga = &A[(size_t)(m0 + srow) * K + scol];
    const u16* gb = &B[(size_t)(n0 + srow) * K + scol];
    const int rsw = (lg ^ ((l15 >> 1) & 3)) * 8;

    f32x4 acc[4][4] = {};
    const int nk = K >> 5;

    auto stage = [&](int buf, int koff) {
        u16* la = &As[buf][wid * 1024];
        u16* lb = &Bs[buf][wid * 1024];
        gload_lds16(ga + koff, la);
        gload_lds16(ga + koff + 16 * K, la + 512);
        gload_lds16(gb + koff, lb);
        gload_lds16(gb + koff + 16 * K, lb + 512);
    };

    stage(0, 0);
    for (int kk = 0; kk < nk; ++kk) {
        const int cur = kk & 1;
        if (kk + 1 < nk) {
            stage(cur ^ 1, (kk + 1) * 32);
            asm volatile("s_waitcnt vmcnt(4)" ::: "memory");
        } else {
            asm volatile("s_waitcnt vmcnt(0)" ::: "memory");
        }
        __builtin_amdgcn_s_barrier();
        s16x8 af[4], bfr[4];
#pragma unroll
        for (int i = 0; i < 4; ++i) af[i]  = *(const s16x8*)&As[cur][(wr * 64 + i * 16 + l15) * 32 + rsw];
#pragma unroll
        for (int j = 0; j < 4; ++j) bfr[j] = *(const s16x8*)&Bs[cur][(wc * 64 + j * 16 + l15) * 32 + rsw];
#pragma unroll
        for (int i = 0; i < 4; ++i)
#pragma unroll
            for (int j = 0; j < 4; ++j)
                acc[i][j] = __builtin_amdgcn_mfma_f32_16x16x32_bf16(af[i], bfr[j], acc[i][j], 0, 0, 0);
        __builtin_amdgcn_s_barrier();
    }
#pragma unroll
    for (int i = 0; i < 4; ++i) {
        int r0 = m0 + wr * 64 + i * 16 + lg * 4;
#pragma unroll
        for (int j = 0; j < 4; ++j) {
            int cc = n0 + wc * 64 + j * 16 + l15;
#pragma unroll
            for (int r = 0; r < 4; ++r) {
                if (OUT_BF16)
                    ((u16*)Cv)[(size_t)(r0 + r) * N + cc] = f2bf(acc[i][j][r]);
                else
                    ((float*)Cv)[(size_t)(r0 + r) * N + cc] = acc[i][j][r];
            }
        }
    }
}

// ---------------- Fused RMSNorm+RoPE and V-transpose ----------------
__global__ __launch_bounds__(256) void nr_vt_kern(
    const u16* __restrict__ qkv, const float* __restrict__ qw,
    const float* __restrict__ kw, u16* __restrict__ qr, u16* __restrict__ kr,
    u16* __restrict__ vt)
{
    __shared__ u16 Ts[128][66];
    const int id = blockIdx.x, tid = threadIdx.x;
    if (id < 20480) {
        const int t = id & 2047, h = (id >> 11) * 4 + (tid >> 6);
        const int i = tid & 63;
        const size_t rowbase = (size_t)t * QKV_N;
        const u16* src; const float* w; u16* dst;
        if (h < 32) {
            src = qkv + rowbase + h * HD; w = qw;
            dst = qr + ((size_t)h * T_SEQ + t) * HD;
        } else {
            int kh = h - 32;
            src = qkv + rowbase + NQ * HD + kh * HD; w = kw;
            dst = kr + ((size_t)kh * T_SEQ + t) * HD;
        }
        float x1 = b2f(src[i]), x2 = b2f(src[i + 64]);
        float ss = x1 * x1 + x2 * x2;
#pragma unroll
        for (int d = 32; d >= 1; d >>= 1) ss += __shfl_xor(ss, d);
        float rs = rsqrtf(ss * (1.0f / 128.0f) + 1e-6f);
        x1 *= rs * w[i];
        x2 *= rs * w[i + 64];
        float ang = (float)t * exp2f((float)i * -0.20762050593567985f);
        float sn, cs;
        sincosf(ang, &sn, &cs);
        dst[i]      = f2bf(x1 * cs - x2 * sn);
        dst[i + 64] = f2bf(x2 * cs + x1 * sn);
        return;
    }
    const int id2 = id - 20480;
    const int t0 = (id2 & 31) * 64, kh = id2 >> 5;
#pragma unroll
    for (int it = 0; it < 4; ++it) {
        int slot = tid + it * 256;
        int tl = slot >> 4, dc = (slot & 15) * 8;
        s16x8 v = *(const s16x8*)&qkv[(size_t)(t0 + tl) * QKV_N + (NQ + NKV) * HD + kh * HD + dc];
#pragma unroll
        for (int e = 0; e < 8; ++e) Ts[dc + e][tl] = (u16)v[e];
    }
    __syncthreads();
#pragma unroll
    for (int it = 0; it < 4; ++it) {
        int slot = tid + it * 256;
        int d = slot >> 3, c = (slot & 7) * 8;
        s16x8 v = *(const s16x8*)&Ts[d][c];
        *(s16x8*)&vt[((size_t)kh * HD + d) * T_SEQ + t0 + c] = v;
    }
}

// ---------------- Flash attention (causal, GQA), swapped-QK^T, QBLK=128 --------
#define KS(b, r, c) Ks[(b)][((r) << 7) + ((c) ^ (((r) & 7) << 3))]
#define VS(b, r, c) Vs[(b)][((r) << 6) + ((c) ^ (((r) & 7) << 3))]
#define PS(wv, r, c) Ps[((wv) << 10) + ((r) << 6) + ((c) ^ (((r) & 7) << 3))]

__global__ __launch_bounds__(512) void attn_kern(
    const u16* __restrict__ qr, const u16* __restrict__ kr,
    const u16* __restrict__ vt, u16* __restrict__ o,
    const float* __restrict__ wo, u16* __restrict__ wo_bf)
{
    __shared__ u16 Ks[2][64 * 128];
    __shared__ u16 Vs[2][128 * 64];
    __shared__ u16 Ps[8 * 16 * 64];
    const int tid = threadIdx.x, lane = tid & 63, w = tid >> 6;
    const int lg = lane >> 4, l15 = lane & 15;
    const int fb = (int)blockIdx.y * 8 + (int)blockIdx.x;
    const int flat = xcd_swz(fb, 256);
    const int qh = flat >> 3, bx = flat & 7;
    const int kvh = qh >> 2;
    const float scale2 = 0.08838834764831845f * 1.4426950408889634f;

    const int cvbase = fb * 8192 + tid;
    int cv = 0;
    float4 cva = {}, cvb = {};

    const int krow = tid >> 4, kcol = (tid & 15) * 8;
    const int vrow = tid >> 3, vcol = (tid & 7) * 8;
    const u16* krbase = kr + (size_t)kvh * T_SEQ * HD;
    const u16* vtbase = vt + (size_t)kvh * HD * T_SEQ;

    s16x8 kst[2], vst[2];
#define LOADKV(k0_) do { \
    kst[0] = *(const s16x8*)&krbase[(size_t)((k0_) + krow) * HD + kcol]; \
    kst[1] = *(const s16x8*)&krbase[(size_t)((k0_) + krow + 32) * HD + kcol]; \
    vst[0] = *(const s16x8*)&vtbase[(size_t)(vrow) * T_SEQ + (k0_) + vcol]; \
    vst[1] = *(const s16x8*)&vtbase[(size_t)(vrow + 64) * T_SEQ + (k0_) + vcol]; \
    } while (0)
#define WRITEKV(b) do { \
    *(s16x8*)&KS((b), krow, kcol) = kst[0]; \
    *(s16x8*)&KS((b), krow + 32, kcol) = kst[1]; \
    *(s16x8*)&VS((b), vrow, vcol) = vst[0]; \
    *(s16x8*)&VS((b), vrow + 64, vcol) = vst[1]; \
    } while (0)

    for (int half = 0; half < 2; ++half) {
        const int q0 = (half == 0) ? bx * 128 : (T_SEQ - 128) - bx * 128;
        s16x8 qf[4];
        {
            const u16* qb = qr + ((size_t)qh * T_SEQ + q0 + w * 16 + l15) * HD;
#pragma unroll
            for (int dc = 0; dc < 4; ++dc) qf[dc] = *(const s16x8*)&qb[dc * 32 + lg * 8];
        }
        f32x4 oacc[8] = {};
        float mQ = -1e30f, lsQ = 0.f;

        const int ktiles = (q0 >> 6) + 2;
        LOADKV(0);
        WRITEKV(0);
        __syncthreads();
        for (int kt = 0; kt < ktiles; ++kt) {
            const int k0 = kt * 64;
            const int cur = kt & 1;
            if (kt + 1 < ktiles) LOADKV(k0 + 64);

            if (cv <= 16) {
                if (cv > 0) {
                    s16x8 o8;
                    o8[0] = (short)f2bf(cva.x); o8[1] = (short)f2bf(cva.y);
                    o8[2] = (short)f2bf(cva.z); o8[3] = (short)f2bf(cva.w);
                    o8[4] = (short)f2bf(cvb.x); o8[5] = (short)f2bf(cvb.y);
                    o8[6] = (short)f2bf(cvb.z); o8[7] = (short)f2bf(cvb.w);
                    ((s16x8*)wo_bf)[cvbase + (cv - 1) * 512] = o8;
                }
                if (cv < 16) {
                    cva = ((const float4*)wo)[2 * (cvbase + cv * 512)];
                    cvb = ((const float4*)wo)[2 * (cvbase + cv * 512) + 1];
                }
                ++cv;
            }

            f32x4 sc[4] = {};
            __builtin_amdgcn_s_setprio(1);
#pragma unroll
            for (int nc = 0; nc < 4; ++nc)
#pragma unroll
                for (int dc = 0; dc < 4; ++dc) {
                    s16x8 kf = *(const s16x8*)&KS(cur, nc * 16 + l15, dc * 32 + lg * 8);
                    sc[nc] = __builtin_amdgcn_mfma_f32_16x16x32_bf16(kf, qf[dc], sc[nc], 0, 0, 0);
                }
            __builtin_amdgcn_s_setprio(0);

            const int qg = q0 + w * 16 + l15;
            const bool needMask = (k0 + 63) > (q0 + w * 16);
            float tm = -1e30f;
#pragma unroll
            for (int nc = 0; nc < 4; ++nc)
#pragma unroll
                for (int r = 0; r < 4; ++r) {
                    float v = sc[nc][r] * scale2;
                    int kg = k0 + nc * 16 + lg * 4 + r;
                    if (needMask && kg > qg) v = -1e30f;
                    sc[nc][r] = v;
                    tm = fmaxf(tm, v);
                }
            tm = fmaxf(tm, __shfl_xor(tm, 16));
            tm = fmaxf(tm, __shfl_xor(tm, 32));

            if (__any(tm > mQ + 8.0f)) {
                float mn = fmaxf(mQ, tm);
                float alpha = exp2f(mQ - mn);
                mQ = mn;
                lsQ *= alpha;
                float aq[4];
#pragma unroll
                for (int r = 0; r < 4; ++r) aq[r] = __shfl(alpha, lg * 4 + r);
#pragma unroll
                for (int dc = 0; dc < 8; ++dc)
#pragma unroll
                    for (int r = 0; r < 4; ++r) oacc[dc][r] *= aq[r];
            }

            float ts = 0.f;
#pragma unroll
            for (int nc = 0; nc < 4; ++nc) {
                s16x4 pk;
#pragma unroll
                for (int r = 0; r < 4; ++r) {
                    float e = exp2f(sc[nc][r] - mQ);
                    ts += e;
                    pk[r] = (short)f2bf(e);
                }
                *(s16x4*)&PS(w, l15, nc * 16 + lg * 4) = pk;
            }
            ts += __shfl_xor(ts, 16);
            ts += __shfl_xor(ts, 32);
            lsQ += ts;

            __builtin_amdgcn_s_setprio(1);
#pragma unroll
            for (int kc = 0; kc < 2; ++kc) {
                s16x8 pf = *(const s16x8*)&PS(w, l15, kc * 32 + lg * 8);
#pragma unroll
                for (int dc = 0; dc < 8; ++dc) {
                    s16x8 vf = *(const s16x8*)&VS(cur, dc * 16 + l15, kc * 32 + lg * 8);
                    oacc[dc] = __builtin_amdgcn_mfma_f32_16x16x32_bf16(pf, vf, oacc[dc], 0, 0, 0);
                }
            }
            __builtin_amdgcn_s_setprio(0);

            if (kt + 1 < ktiles) WRITEKV(cur ^ 1);
            __syncthreads();
        }
        float lq[4];
#pragma unroll
        for (int r = 0; r < 4; ++r) lq[r] = __shfl(lsQ, lg * 4 + r);
#pragma unroll
        for (int r = 0; r < 4; ++r) {
            float inv = 1.0f / lq[r];
            int trow = q0 + w * 16 + lg * 4 + r;
            u16* dst = o + (size_t)trow * (NQ * HD) + qh * HD;
#pragma unroll
            for (int dc = 0; dc < 8; ++dc) dst[dc * 16 + l15] = f2bf(oacc[dc][r] * inv);
        }
    }
#undef LOADKV
#undef WRITEKV
}

extern "C" void kernel_launch(void* const* d_in, const int* in_sizes, int n_in,
                              void* d_out, int out_size, void* d_ws, size_t ws_size,
                              hipStream_t stream)
{
    const float* hs   = (const float*)d_in[0];
    const float* wqkv = (const float*)d_in[1];
    const float* qw   = (const float*)d_in[2];
    const float* kw   = (const float*)d_in[3];
    const float* wo   = (const float*)d_in[4];
    float* out = (float*)d_out;

    // workspace 92,274,688 B (88 MiB). Fully disjoint live regions per stage:
    //   gemm1: R hs_bf[0,16M) + wqkv_bf[40,88M)  -> W qkv_bf[16,40M)
    //   nr_vt: R qkv_bf[16,40M)                  -> W qr[64,80M) kr[80,84M) vt[84,88M)
    //   attn : R qr/kr/vt[64,88M) + wo(input)    -> W ob[0,16M) + wo_bf[16,48M)
    //   gemm2: R ob[0,16M) + wo_bf[16,48M)       -> W d_out
    char* ws = (char*)d_ws;
    u16* hs_bf   = (u16*)(ws);                  // [0,16M)
    u16* ob      = (u16*)(ws);                  // [0,16M)  (after gemm1)
    u16* qkv_bf  = (u16*)(ws + 16777216);       // [16,40M)
    u16* wo_bf   = (u16*)(ws + 16777216);       // [16,48M) (after nr_vt)
    u16* wqkv_bf = (u16*)(ws + 41943040);       // [40,88M)
    u16* qr      = (u16*)(ws + 67108864);       // [64,80M)
    u16* kr      = (u16*)(ws + 83886080);       // [80,84M)
    u16* vt      = (u16*)(ws + 88080384);       // [84,88M)

    // 1) convert hs + wqkv
    conv2_bf16_kern<<<2048, 256, 0, stream>>>(
        hs, hs_bf, T_SEQ * HIDDEN / 8, wqkv, wqkv_bf, QKV_N * HIDDEN / 8);
    // 2) qkv = hs @ wqkv^T  (256x192 8-phase, 256 blocks = 1/CU)
    gemm1_8ph<<<dim3(QKV_N / 192, T_SEQ / 256), 512, 0, stream>>>(
        hs_bf, wqkv_bf, qkv_bf, QKV_N, HIDDEN);
    // 3) fused norm+rope / V-transpose (last reader of qkv_bf)
    nr_vt_kern<<<20736, 256, 0, stream>>>(qkv_bf, qw, kw, qr, kr, vt);
    // 4) attention with embedded wo conversion
    attn_kern<<<dim3(8, NQ), 512, 0, stream>>>(qr, kr, vt, ob, wo, wo_bf);
    // 5) out = o @ wo^T  (128² 2-phase, 512 blocks = 2/CU)
    gemm_bt_bf16<0><<<dim3(HIDDEN / 128, T_SEQ / 128), 256, 0, stream>>>(
        ob, wo_bf, (void*)out, HIDDEN, HIDDEN);
}

// Round 22
// 315.226 us; speedup vs baseline: 1.0438x; 1.0210x over previous
//
#include <hip/hip_runtime.h>
#include <hip/hip_bf16.h>

typedef float f32x4 __attribute__((ext_vector_type(4)));
typedef short s16x8 __attribute__((ext_vector_type(8)));
typedef short s16x4 __attribute__((ext_vector_type(4)));
typedef unsigned short u16;

#define HIDDEN 4096
#define NQ 32
#define NKV 8
#define HD 128
#define T_SEQ 2048
#define QKV_N ((NQ + 2 * NKV) * HD)   // 6144

__device__ __forceinline__ u16 f2bf(float f) {
    union { float f; unsigned u; } v; v.f = f;
    unsigned r = v.u + 0x7FFFu + ((v.u >> 16) & 1u);
    return (u16)(r >> 16);
}
__device__ __forceinline__ float b2f(u16 h) {
    union { unsigned u; float f; } v; v.u = ((unsigned)h) << 16; return v.f;
}
__device__ __forceinline__ void gload_lds16(const u16* g, u16* l) {
    __builtin_amdgcn_global_load_lds(
        (const __attribute__((address_space(1))) unsigned int*)g,
        (__attribute__((address_space(3))) unsigned int*)l,
        16, 0, 0);
}
// bijective XCD remap (nwg % 8 == 0): contiguous chunk per XCD
__device__ __forceinline__ int xcd_swz(int flat, int nwg) {
    return (flat & 7) * (nwg >> 3) + (flat >> 3);
}

// ---------------- f32 -> bf16 bulk convert (two segments) ----------------
__device__ __forceinline__ void conv8(const float* src, u16* dst, int i) {
    const float4 a = ((const float4*)src)[2 * i];
    const float4 b = ((const float4*)src)[2 * i + 1];
    s16x8 o;
    o[0] = (short)f2bf(a.x); o[1] = (short)f2bf(a.y);
    o[2] = (short)f2bf(a.z); o[3] = (short)f2bf(a.w);
    o[4] = (short)f2bf(b.x); o[5] = (short)f2bf(b.y);
    o[6] = (short)f2bf(b.z); o[7] = (short)f2bf(b.w);
    ((s16x8*)dst)[i] = o;
}
__global__ __launch_bounds__(256) void conv2_bf16_kern(
    const float* __restrict__ s1, u16* __restrict__ d1, int n1,
    const float* __restrict__ s2, u16* __restrict__ d2, int n2)
{
    for (int i = blockIdx.x * 256 + threadIdx.x; i < n1 + n2; i += gridDim.x * 256) {
        if (i < n1) conv8(s1, d1, i);
        else        conv8(s2, d2, i - n1);
    }
}

// ============ gemm1: 256x192, BK=64, 4-sync-phase counted-vmcnt (r22) =======
// r17/r21 skeleton with phase pairs MERGED: 2 compute phases/tile (mh0, mh1),
// 24 MFMA each, 4 barriers/tile (was 8). Same slot-parity invariant
// (tile tau in slot tau&1) and staging safety:
//   ph1(mh0): read af(both kh)+bq(both kh); stage A[s^1]{c1,c3}(t+1) +
//             B[s^1]{c0,c1,c2}(t+1)  [regions last read at tile t-1]
//   ph2(mh1): read af{c1,c3}, reuse bq; stage A[s]{c0,c2}(t+2)
//             [A[s]{c0,c2} last read in ph1; reads complete before ph1's
//              trailing barrier since MFMAs consume them]
//   tile-end: vmcnt(2) (queue = ph1's 5 (t+1) + ph2's 2 (t+2) -> drains t+1);
//             tails vmcnt(0). Prologue: 9 loads, vmcnt(2).
// mh chunk map: mh0 -> rows {c0,c2}, mh1 -> rows {c1,c3} (wr interleave).
__global__ __launch_bounds__(512) void gemm1_4ph(
    const u16* __restrict__ A, const u16* __restrict__ B,
    u16* __restrict__ C, int N, int K)
{
    __shared__ u16 As[2][256 * 64];
    __shared__ u16 Bs[2][192 * 64];
    const int tid = threadIdx.x, lane = tid & 63, wid = tid >> 6;
    const int wr = wid >> 2, wc = wid & 3;
    const int lg = lane >> 4, l15 = lane & 15;
    const int m0 = blockIdx.y * 256, n0 = blockIdx.x * 192;
    const int nk = K >> 6;
    const int r8 = lane >> 3;
    const int csw = ((lane & 7) ^ r8) * 8;

    f32x4 acc[8][3] = {};
    s16x8 af[4][2], bq[3][2];

    auto stageA = [&](int sl, int c, int kt) {
        gload_lds16(&A[(size_t)(m0 + c * 64 + wid * 8 + r8) * K + kt * 64 + csw],
                    &As[sl][(c * 64 + wid * 8) * 64]);
    };
    auto stageB = [&](int sl, int c, int kt) {
        gload_lds16(&B[(size_t)(n0 + c * 64 + wid * 8 + r8) * K + kt * 64 + csw],
                    &Bs[sl][(c * 64 + wid * 8) * 64]);
    };
    auto ldA2 = [&](int s_, int mh_) {
#pragma unroll
        for (int mi = 0; mi < 4; ++mi)
#pragma unroll
            for (int kh = 0; kh < 2; ++kh)
                af[mi][kh] = *(const s16x8*)&As[s_][
                    ((wr * 128 + mh_ * 64 + mi * 16 + l15) << 6) +
                    (((lg + kh * 4) ^ (l15 & 7)) << 3)];
    };
    auto ldB2 = [&](int s_) {
#pragma unroll
        for (int ni = 0; ni < 3; ++ni)
#pragma unroll
            for (int kh = 0; kh < 2; ++kh)
                bq[ni][kh] = *(const s16x8*)&Bs[s_][
                    ((wc * 48 + ni * 16 + l15) << 6) +
                    (((lg + kh * 4) ^ (l15 & 7)) << 3)];
    };
    auto mm2 = [&](int mh_) {
        __builtin_amdgcn_s_setprio(1);
#pragma unroll
        for (int mi = 0; mi < 4; ++mi)
#pragma unroll
            for (int ni = 0; ni < 3; ++ni)
#pragma unroll
                for (int kh = 0; kh < 2; ++kh)
                    acc[mh_ * 4 + mi][ni] =
                        __builtin_amdgcn_mfma_f32_16x16x32_bf16(
                            af[mi][kh], bq[ni][kh], acc[mh_ * 4 + mi][ni], 0, 0, 0);
        __builtin_amdgcn_s_setprio(0);
    };
#define FENCE asm volatile("" ::: "memory");

    // prologue: tile 0 full (7) + tile 1 A{c0,c2} (2); drain tile 0
    stageA(0, 0, 0); stageA(0, 1, 0); stageA(0, 2, 0); stageA(0, 3, 0);
    stageB(0, 0, 0); stageB(0, 1, 0); stageB(0, 2, 0);
    stageA(1, 0, 1); stageA(1, 2, 1);
    asm volatile("s_waitcnt vmcnt(2)" ::: "memory");
    __builtin_amdgcn_s_barrier();

    for (int t = 0; t < nk; ++t) {
        const int s = t & 1;
        // ---- ph1 (mh0): stage t+1 remainder (A c1,c3 + B all)
        ldA2(s, 0); ldB2(s);
        if (t + 1 < nk) {
            stageA(s ^ 1, 1, t + 1); stageA(s ^ 1, 3, t + 1);
            stageB(s ^ 1, 0, t + 1); stageB(s ^ 1, 1, t + 1); stageB(s ^ 1, 2, t + 1);
        }
        FENCE
        __builtin_amdgcn_s_barrier();
        mm2(0);
        FENCE
        __builtin_amdgcn_s_barrier();
        // ---- ph2 (mh1): reuse bq; stage A[s]{c0,c2}(t+2); counted vmcnt
        ldA2(s, 1);
        if (t + 2 < nk) { stageA(s, 0, t + 2); stageA(s, 2, t + 2); }
        FENCE
        __builtin_amdgcn_s_barrier();
        mm2(1);
        if (t + 2 < nk) asm volatile("s_waitcnt vmcnt(2)" ::: "memory");
        else            asm volatile("s_waitcnt vmcnt(0)" ::: "memory");
        FENCE
        __builtin_amdgcn_s_barrier();
    }
#undef FENCE

#pragma unroll
    for (int mh = 0; mh < 2; ++mh)
#pragma unroll
    for (int mi = 0; mi < 4; ++mi)
#pragma unroll
    for (int ni = 0; ni < 3; ++ni) {
        int row0 = m0 + wr * 128 + mh * 64 + mi * 16 + lg * 4;
        int col  = n0 + wc * 48 + ni * 16 + l15;
#pragma unroll
        for (int r = 0; r < 4; ++r)
            C[(size_t)(row0 + r) * N + col] = f2bf(acc[mh * 4 + mi][ni][r]);
    }
}

// ---------------- GEMM (128² 2-phase, proven): C = A * B^T ----------------
template<int OUT_BF16>
__global__ __launch_bounds__(256) void gemm_bt_bf16(
    const u16* __restrict__ A, const u16* __restrict__ B,
    void* __restrict__ Cv, int N, int K)
{
    __shared__ u16 As[2][128 * 32];
    __shared__ u16 Bs[2][128 * 32];
    const int tid = threadIdx.x, lane = tid & 63, wid = tid >> 6;
    const int wr = wid >> 1, wc = wid & 1, lg = lane >> 4, l15 = lane & 15;
    const int m0 = blockIdx.y * 128, n0 = blockIdx.x * 128;
    const int srow = wid * 32 + (lane >> 2);
    const int scol = (((lane & 3) ^ ((lane >> 3) & 3))) * 8;
    const u16* ga = &A[(size_t)(m0 + srow) * K + scol];
    const u16* gb = &B[(size_t)(n0 + srow) * K + scol];
    const int rsw = (lg ^ ((l15 >> 1) & 3)) * 8;

    f32x4 acc[4][4] = {};
    const int nk = K >> 5;

    auto stage = [&](int buf, int koff) {
        u16* la = &As[buf][wid * 1024];
        u16* lb = &Bs[buf][wid * 1024];
        gload_lds16(ga + koff, la);
        gload_lds16(ga + koff + 16 * K, la + 512);
        gload_lds16(gb + koff, lb);
        gload_lds16(gb + koff + 16 * K, lb + 512);
    };

    stage(0, 0);
    for (int kk = 0; kk < nk; ++kk) {
        const int cur = kk & 1;
        if (kk + 1 < nk) {
            stage(cur ^ 1, (kk + 1) * 32);
            asm volatile("s_waitcnt vmcnt(4)" ::: "memory");
        } else {
            asm volatile("s_waitcnt vmcnt(0)" ::: "memory");
        }
        __builtin_amdgcn_s_barrier();
        s16x8 af[4], bfr[4];
#pragma unroll
        for (int i = 0; i < 4; ++i) af[i]  = *(const s16x8*)&As[cur][(wr * 64 + i * 16 + l15) * 32 + rsw];
#pragma unroll
        for (int j = 0; j < 4; ++j) bfr[j] = *(const s16x8*)&Bs[cur][(wc * 64 + j * 16 + l15) * 32 + rsw];
#pragma unroll
        for (int i = 0; i < 4; ++i)
#pragma unroll
            for (int j = 0; j < 4; ++j)
                acc[i][j] = __builtin_amdgcn_mfma_f32_16x16x32_bf16(af[i], bfr[j], acc[i][j], 0, 0, 0);
        __builtin_amdgcn_s_barrier();
    }
#pragma unroll
    for (int i = 0; i < 4; ++i) {
        int r0 = m0 + wr * 64 + i * 16 + lg * 4;
#pragma unroll
        for (int j = 0; j < 4; ++j) {
            int cc = n0 + wc * 64 + j * 16 + l15;
#pragma unroll
            for (int r = 0; r < 4; ++r) {
                if (OUT_BF16)
                    ((u16*)Cv)[(size_t)(r0 + r) * N + cc] = f2bf(acc[i][j][r]);
                else
                    ((float*)Cv)[(size_t)(r0 + r) * N + cc] = acc[i][j][r];
            }
        }
    }
}

// ---------------- Fused RMSNorm+RoPE and V-transpose ----------------
__global__ __launch_bounds__(256) void nr_vt_kern(
    const u16* __restrict__ qkv, const float* __restrict__ qw,
    const float* __restrict__ kw, u16* __restrict__ qr, u16* __restrict__ kr,
    u16* __restrict__ vt)
{
    __shared__ u16 Ts[128][66];
    const int id = blockIdx.x, tid = threadIdx.x;
    if (id < 20480) {
        const int t = id & 2047, h = (id >> 11) * 4 + (tid >> 6);
        const int i = tid & 63;
        const size_t rowbase = (size_t)t * QKV_N;
        const u16* src; const float* w; u16* dst;
        if (h < 32) {
            src = qkv + rowbase + h * HD; w = qw;
            dst = qr + ((size_t)h * T_SEQ + t) * HD;
        } else {
            int kh = h - 32;
            src = qkv + rowbase + NQ * HD + kh * HD; w = kw;
            dst = kr + ((size_t)kh * T_SEQ + t) * HD;
        }
        float x1 = b2f(src[i]), x2 = b2f(src[i + 64]);
        float ss = x1 * x1 + x2 * x2;
#pragma unroll
        for (int d = 32; d >= 1; d >>= 1) ss += __shfl_xor(ss, d);
        float rs = rsqrtf(ss * (1.0f / 128.0f) + 1e-6f);
        x1 *= rs * w[i];
        x2 *= rs * w[i + 64];
        float ang = (float)t * exp2f((float)i * -0.20762050593567985f);
        float sn, cs;
        sincosf(ang, &sn, &cs);
        dst[i]      = f2bf(x1 * cs - x2 * sn);
        dst[i + 64] = f2bf(x2 * cs + x1 * sn);
        return;
    }
    const int id2 = id - 20480;
    const int t0 = (id2 & 31) * 64, kh = id2 >> 5;
#pragma unroll
    for (int it = 0; it < 4; ++it) {
        int slot = tid + it * 256;
        int tl = slot >> 4, dc = (slot & 15) * 8;
        s16x8 v = *(const s16x8*)&qkv[(size_t)(t0 + tl) * QKV_N + (NQ + NKV) * HD + kh * HD + dc];
#pragma unroll
        for (int e = 0; e < 8; ++e) Ts[dc + e][tl] = (u16)v[e];
    }
    __syncthreads();
#pragma unroll
    for (int it = 0; it < 4; ++it) {
        int slot = tid + it * 256;
        int d = slot >> 3, c = (slot & 7) * 8;
        s16x8 v = *(const s16x8*)&Ts[d][c];
        *(s16x8*)&vt[((size_t)kh * HD + d) * T_SEQ + t0 + c] = v;
    }
}

// ---------------- Flash attention (causal, GQA), swapped-QK^T, QBLK=128 --------
#define KS(b, r, c) Ks[(b)][((r) << 7) + ((c) ^ (((r) & 7) << 3))]
#define VS(b, r, c) Vs[(b)][((r) << 6) + ((c) ^ (((r) & 7) << 3))]
#define PS(wv, r, c) Ps[((wv) << 10) + ((r) << 6) + ((c) ^ (((r) & 7) << 3))]

__global__ __launch_bounds__(512) void attn_kern(
    const u16* __restrict__ qr, const u16* __restrict__ kr,
    const u16* __restrict__ vt, u16* __restrict__ o,
    const float* __restrict__ wo, u16* __restrict__ wo_bf)
{
    __shared__ u16 Ks[2][64 * 128];
    __shared__ u16 Vs[2][128 * 64];
    __shared__ u16 Ps[8 * 16 * 64];
    const int tid = threadIdx.x, lane = tid & 63, w = tid >> 6;
    const int lg = lane >> 4, l15 = lane & 15;
    const int fb = (int)blockIdx.y * 8 + (int)blockIdx.x;
    const int flat = xcd_swz(fb, 256);
    const int qh = flat >> 3, bx = flat & 7;
    const int kvh = qh >> 2;
    const float scale2 = 0.08838834764831845f * 1.4426950408889634f;

    const int cvbase = fb * 8192 + tid;
    int cv = 0;
    float4 cva = {}, cvb = {};

    const int krow = tid >> 4, kcol = (tid & 15) * 8;
    const int vrow = tid >> 3, vcol = (tid & 7) * 8;
    const u16* krbase = kr + (size_t)kvh * T_SEQ * HD;
    const u16* vtbase = vt + (size_t)kvh * HD * T_SEQ;

    s16x8 kst[2], vst[2];
#define LOADKV(k0_) do { \
    kst[0] = *(const s16x8*)&krbase[(size_t)((k0_) + krow) * HD + kcol]; \
    kst[1] = *(const s16x8*)&krbase[(size_t)((k0_) + krow + 32) * HD + kcol]; \
    vst[0] = *(const s16x8*)&vtbase[(size_t)(vrow) * T_SEQ + (k0_) + vcol]; \
    vst[1] = *(const s16x8*)&vtbase[(size_t)(vrow + 64) * T_SEQ + (k0_) + vcol]; \
    } while (0)
#define WRITEKV(b) do { \
    *(s16x8*)&KS((b), krow, kcol) = kst[0]; \
    *(s16x8*)&KS((b), krow + 32, kcol) = kst[1]; \
    *(s16x8*)&VS((b), vrow, vcol) = vst[0]; \
    *(s16x8*)&VS((b), vrow + 64, vcol) = vst[1]; \
    } while (0)

    for (int half = 0; half < 2; ++half) {
        const int q0 = (half == 0) ? bx * 128 : (T_SEQ - 128) - bx * 128;
        s16x8 qf[4];
        {
            const u16* qb = qr + ((size_t)qh * T_SEQ + q0 + w * 16 + l15) * HD;
#pragma unroll
            for (int dc = 0; dc < 4; ++dc) qf[dc] = *(const s16x8*)&qb[dc * 32 + lg * 8];
        }
        f32x4 oacc[8] = {};
        float mQ = -1e30f, lsQ = 0.f;

        const int ktiles = (q0 >> 6) + 2;
        LOADKV(0);
        WRITEKV(0);
        __syncthreads();
        for (int kt = 0; kt < ktiles; ++kt) {
            const int k0 = kt * 64;
            const int cur = kt & 1;
            if (kt + 1 < ktiles) LOADKV(k0 + 64);

            if (cv <= 16) {
                if (cv > 0) {
                    s16x8 o8;
                    o8[0] = (short)f2bf(cva.x); o8[1] = (short)f2bf(cva.y);
                    o8[2] = (short)f2bf(cva.z); o8[3] = (short)f2bf(cva.w);
                    o8[4] = (short)f2bf(cvb.x); o8[5] = (short)f2bf(cvb.y);
                    o8[6] = (short)f2bf(cvb.z); o8[7] = (short)f2bf(cvb.w);
                    ((s16x8*)wo_bf)[cvbase + (cv - 1) * 512] = o8;
                }
                if (cv < 16) {
                    cva = ((const float4*)wo)[2 * (cvbase + cv * 512)];
                    cvb = ((const float4*)wo)[2 * (cvbase + cv * 512) + 1];
                }
                ++cv;
            }

            f32x4 sc[4] = {};
            __builtin_amdgcn_s_setprio(1);
#pragma unroll
            for (int nc = 0; nc < 4; ++nc)
#pragma unroll
                for (int dc = 0; dc < 4; ++dc) {
                    s16x8 kf = *(const s16x8*)&KS(cur, nc * 16 + l15, dc * 32 + lg * 8);
                    sc[nc] = __builtin_amdgcn_mfma_f32_16x16x32_bf16(kf, qf[dc], sc[nc], 0, 0, 0);
                }
            __builtin_amdgcn_s_setprio(0);

            const int qg = q0 + w * 16 + l15;
            const bool needMask = (k0 + 63) > (q0 + w * 16);
            float tm = -1e30f;
#pragma unroll
            for (int nc = 0; nc < 4; ++nc)
#pragma unroll
                for (int r = 0; r < 4; ++r) {
                    float v = sc[nc][r] * scale2;
                    int kg = k0 + nc * 16 + lg * 4 + r;
                    if (needMask && kg > qg) v = -1e30f;
                    sc[nc][r] = v;
                    tm = fmaxf(tm, v);
                }
            tm = fmaxf(tm, __shfl_xor(tm, 16));
            tm = fmaxf(tm, __shfl_xor(tm, 32));

            if (__any(tm > mQ + 8.0f)) {
                float mn = fmaxf(mQ, tm);
                float alpha = exp2f(mQ - mn);
                mQ = mn;
                lsQ *= alpha;
                float aq[4];
#pragma unroll
                for (int r = 0; r < 4; ++r) aq[r] = __shfl(alpha, lg * 4 + r);
#pragma unroll
                for (int dc = 0; dc < 8; ++dc)
#pragma unroll
                    for (int r = 0; r < 4; ++r) oacc[dc][r] *= aq[r];
            }

            float ts = 0.f;
#pragma unroll
            for (int nc = 0; nc < 4; ++nc) {
                s16x4 pk;
#pragma unroll
                for (int r = 0; r < 4; ++r) {
                    float e = exp2f(sc[nc][r] - mQ);
                    ts += e;
                    pk[r] = (short)f2bf(e);
                }
                *(s16x4*)&PS(w, l15, nc * 16 + lg * 4) = pk;
            }
            ts += __shfl_xor(ts, 16);
            ts += __shfl_xor(ts, 32);
            lsQ += ts;

            __builtin_amdgcn_s_setprio(1);
#pragma unroll
            for (int kc = 0; kc < 2; ++kc) {
                s16x8 pf = *(const s16x8*)&PS(w, l15, kc * 32 + lg * 8);
#pragma unroll
                for (int dc = 0; dc < 8; ++dc) {
                    s16x8 vf = *(const s16x8*)&VS(cur, dc * 16 + l15, kc * 32 + lg * 8);
                    oacc[dc] = __builtin_amdgcn_mfma_f32_16x16x32_bf16(pf, vf, oacc[dc], 0, 0, 0);
                }
            }
            __builtin_amdgcn_s_setprio(0);

            if (kt + 1 < ktiles) WRITEKV(cur ^ 1);
            __syncthreads();
        }
        float lq[4];
#pragma unroll
        for (int r = 0; r < 4; ++r) lq[r] = __shfl(lsQ, lg * 4 + r);
#pragma unroll
        for (int r = 0; r < 4; ++r) {
            float inv = 1.0f / lq[r];
            int trow = q0 + w * 16 + lg * 4 + r;
            u16* dst = o + (size_t)trow * (NQ * HD) + qh * HD;
#pragma unroll
            for (int dc = 0; dc < 8; ++dc) dst[dc * 16 + l15] = f2bf(oacc[dc][r] * inv);
        }
    }
#undef LOADKV
#undef WRITEKV
}

extern "C" void kernel_launch(void* const* d_in, const int* in_sizes, int n_in,
                              void* d_out, int out_size, void* d_ws, size_t ws_size,
                              hipStream_t stream)
{
    const float* hs   = (const float*)d_in[0];
    const float* wqkv = (const float*)d_in[1];
    const float* qw   = (const float*)d_in[2];
    const float* kw   = (const float*)d_in[3];
    const float* wo   = (const float*)d_in[4];
    float* out = (float*)d_out;

    // workspace 92,274,688 B (88 MiB). Fully disjoint live regions per stage:
    //   gemm1: R hs_bf[0,16M) + wqkv_bf[40,88M)  -> W qkv_bf[16,40M)
    //   nr_vt: R qkv_bf[16,40M)                  -> W qr[64,80M) kr[80,84M) vt[84,88M)
    //   attn : R qr/kr/vt[64,88M) + wo(input)    -> W ob[0,16M) + wo_bf[16,48M)
    //   gemm2: R ob[0,16M) + wo_bf[16,48M)       -> W d_out
    char* ws = (char*)d_ws;
    u16* hs_bf   = (u16*)(ws);                  // [0,16M)
    u16* ob      = (u16*)(ws);                  // [0,16M)  (after gemm1)
    u16* qkv_bf  = (u16*)(ws + 16777216);       // [16,40M)
    u16* wo_bf   = (u16*)(ws + 16777216);       // [16,48M) (after nr_vt)
    u16* wqkv_bf = (u16*)(ws + 41943040);       // [40,88M)
    u16* qr      = (u16*)(ws + 67108864);       // [64,80M)
    u16* kr      = (u16*)(ws + 83886080);       // [80,84M)
    u16* vt      = (u16*)(ws + 88080384);       // [84,88M)

    // 1) convert hs + wqkv
    conv2_bf16_kern<<<2048, 256, 0, stream>>>(
        hs, hs_bf, T_SEQ * HIDDEN / 8, wqkv, wqkv_bf, QKV_N * HIDDEN / 8);
    // 2) qkv = hs @ wqkv^T  (256x192 4-sync-phase, 256 blocks = 1/CU)
    gemm1_4ph<<<dim3(QKV_N / 192, T_SEQ / 256), 512, 0, stream>>>(
        hs_bf, wqkv_bf, qkv_bf, QKV_N, HIDDEN);
    // 3) fused norm+rope / V-transpose (last reader of qkv_bf)
    nr_vt_kern<<<20736, 256, 0, stream>>>(qkv_bf, qw, kw, qr, kr, vt);
    // 4) attention with embedded wo conversion
    attn_kern<<<dim3(8, NQ), 512, 0, stream>>>(qr, kr, vt, ob, wo, wo_bf);
    // 5) out = o @ wo^T  (128² 2-phase, 512 blocks = 2/CU)
    gemm_bt_bf16<0><<<dim3(HIDDEN / 128, T_SEQ / 128), 256, 0, stream>>>(
        ob, wo_bf, (void*)out, HIDDEN, HIDDEN);
}

// Round 23
// 303.650 us; speedup vs baseline: 1.0836x; 1.0381x over previous
//
#include <hip/hip_runtime.h>
#include <hip/hip_bf16.h>

typedef float f32x4 __attribute__((ext_vector_type(4)));
typedef short s16x8 __attribute__((ext_vector_type(8)));
typedef short s16x4 __attribute__((ext_vector_type(4)));
typedef unsigned short u16;

#define HIDDEN 4096
#define NQ 32
#define NKV 8
#define HD 128
#define T_SEQ 2048
#define QKV_N ((NQ + 2 * NKV) * HD)   // 6144

__device__ __forceinline__ u16 f2bf(float f) {
    union { float f; unsigned u; } v; v.f = f;
    unsigned r = v.u + 0x7FFFu + ((v.u >> 16) & 1u);
    return (u16)(r >> 16);
}
__device__ __forceinline__ float b2f(u16 h) {
    union { unsigned u; float f; } v; v.u = ((unsigned)h) << 16; return v.f;
}
__device__ __forceinline__ void gload_lds16(const u16* g, u16* l) {
    __builtin_amdgcn_global_load_lds(
        (const __attribute__((address_space(1))) unsigned int*)g,
        (__attribute__((address_space(3))) unsigned int*)l,
        16, 0, 0);
}
// bijective XCD remap (nwg % 8 == 0): contiguous chunk per XCD
__device__ __forceinline__ int xcd_swz(int flat, int nwg) {
    return (flat & 7) * (nwg >> 3) + (flat >> 3);
}

// ---------------- f32 -> bf16 bulk convert (two segments) ----------------
__device__ __forceinline__ void conv8(const float* src, u16* dst, int i) {
    const float4 a = ((const float4*)src)[2 * i];
    const float4 b = ((const float4*)src)[2 * i + 1];
    s16x8 o;
    o[0] = (short)f2bf(a.x); o[1] = (short)f2bf(a.y);
    o[2] = (short)f2bf(a.z); o[3] = (short)f2bf(a.w);
    o[4] = (short)f2bf(b.x); o[5] = (short)f2bf(b.y);
    o[6] = (short)f2bf(b.z); o[7] = (short)f2bf(b.w);
    ((s16x8*)dst)[i] = o;
}
__global__ __launch_bounds__(256) void conv2_bf16_kern(
    const float* __restrict__ s1, u16* __restrict__ d1, int n1,
    const float* __restrict__ s2, u16* __restrict__ d2, int n2)
{
    for (int i = blockIdx.x * 256 + threadIdx.x; i < n1 + n2; i += gridDim.x * 256) {
        if (i < n1) conv8(s1, d1, i);
        else        conv8(s2, d2, i - n1);
    }
}

// ============ 4-sync-phase GEMM: C[M,N]=A*B^T, tile 256 x (NI*64) ==========
// r22-proven structure, templated. 512 thr = 8 waves (2M x 4N); per-wave out
// 128 x NI*16 (acc[8][NI]). 2 compute phases/tile (mh0, mh1), 8*NI MFMA each,
// 4 barriers/tile. Slot-parity invariant (tile tau in slot tau&1):
//   ph1(mh0): read af(both kh)+bq(both kh); stage A[s^1]{c1,c3}(t+1) +
//             B[s^1]{c0..cNI-1}(t+1)  [regions last read at tile t-1]
//   ph2(mh1): read af{c1,c3}, reuse bq; stage A[s]{c0,c2}(t+2)
//   tile-end: vmcnt(2) — queue = ph1's (2+NI) (t+1) + ph2's 2 (t+2); drains
//             ph1's AND older ph2(t-1)'s (t+1 A-part) -> t+1 fully landed;
//             tails vmcnt(0). Prologue: (4+NI)+2 loads, vmcnt(2).
// gemm1: NI=3 (256x192, 32x8 grid); gemm2: NI=2 (256x128, 32x8 grid).
template<int NI, int OUT_BF16>
__global__ __launch_bounds__(512) void gemm_4ph(
    const u16* __restrict__ A, const u16* __restrict__ B,
    void* __restrict__ Cv, int N, int K)
{
    __shared__ u16 As[2][256 * 64];
    __shared__ u16 Bs[2][NI * 64 * 64];
    const int tid = threadIdx.x, lane = tid & 63, wid = tid >> 6;
    const int wr = wid >> 2, wc = wid & 3;
    const int lg = lane >> 4, l15 = lane & 15;
    const int m0 = blockIdx.y * 256, n0 = blockIdx.x * (NI * 64);
    const int nk = K >> 6;
    const int r8 = lane >> 3;
    const int csw = ((lane & 7) ^ r8) * 8;

    f32x4 acc[8][NI] = {};
    s16x8 af[4][2], bq[NI][2];

    auto stageA = [&](int sl, int c, int kt) {
        gload_lds16(&A[(size_t)(m0 + c * 64 + wid * 8 + r8) * K + kt * 64 + csw],
                    &As[sl][(c * 64 + wid * 8) * 64]);
    };
    auto stageB = [&](int sl, int c, int kt) {
        gload_lds16(&B[(size_t)(n0 + c * 64 + wid * 8 + r8) * K + kt * 64 + csw],
                    &Bs[sl][(c * 64 + wid * 8) * 64]);
    };
    auto ldA2 = [&](int s_, int mh_) {
#pragma unroll
        for (int mi = 0; mi < 4; ++mi)
#pragma unroll
            for (int kh = 0; kh < 2; ++kh)
                af[mi][kh] = *(const s16x8*)&As[s_][
                    ((wr * 128 + mh_ * 64 + mi * 16 + l15) << 6) +
                    (((lg + kh * 4) ^ (l15 & 7)) << 3)];
    };
    auto ldB2 = [&](int s_) {
#pragma unroll
        for (int ni = 0; ni < NI; ++ni)
#pragma unroll
            for (int kh = 0; kh < 2; ++kh)
                bq[ni][kh] = *(const s16x8*)&Bs[s_][
                    ((wc * (NI * 16) + ni * 16 + l15) << 6) +
                    (((lg + kh * 4) ^ (l15 & 7)) << 3)];
    };
    auto mm2 = [&](int mh_) {
        __builtin_amdgcn_s_setprio(1);
#pragma unroll
        for (int mi = 0; mi < 4; ++mi)
#pragma unroll
            for (int ni = 0; ni < NI; ++ni)
#pragma unroll
                for (int kh = 0; kh < 2; ++kh)
                    acc[mh_ * 4 + mi][ni] =
                        __builtin_amdgcn_mfma_f32_16x16x32_bf16(
                            af[mi][kh], bq[ni][kh], acc[mh_ * 4 + mi][ni], 0, 0, 0);
        __builtin_amdgcn_s_setprio(0);
    };
#define FENCE asm volatile("" ::: "memory");

    // prologue: tile 0 full (4+NI) + tile 1 A{c0,c2} (2); drain tile 0
    stageA(0, 0, 0); stageA(0, 1, 0); stageA(0, 2, 0); stageA(0, 3, 0);
#pragma unroll
    for (int c = 0; c < NI; ++c) stageB(0, c, 0);
    stageA(1, 0, 1); stageA(1, 2, 1);
    asm volatile("s_waitcnt vmcnt(2)" ::: "memory");
    __builtin_amdgcn_s_barrier();

    for (int t = 0; t < nk; ++t) {
        const int s = t & 1;
        // ---- ph1 (mh0): stage t+1 remainder (A c1,c3 + B all)
        ldA2(s, 0); ldB2(s);
        if (t + 1 < nk) {
            stageA(s ^ 1, 1, t + 1); stageA(s ^ 1, 3, t + 1);
#pragma unroll
            for (int c = 0; c < NI; ++c) stageB(s ^ 1, c, t + 1);
        }
        FENCE
        __builtin_amdgcn_s_barrier();
        mm2(0);
        FENCE
        __builtin_amdgcn_s_barrier();
        // ---- ph2 (mh1): reuse bq; stage A[s]{c0,c2}(t+2); counted vmcnt
        ldA2(s, 1);
        if (t + 2 < nk) { stageA(s, 0, t + 2); stageA(s, 2, t + 2); }
        FENCE
        __builtin_amdgcn_s_barrier();
        mm2(1);
        if (t + 2 < nk) asm volatile("s_waitcnt vmcnt(2)" ::: "memory");
        else            asm volatile("s_waitcnt vmcnt(0)" ::: "memory");
        FENCE
        __builtin_amdgcn_s_barrier();
    }
#undef FENCE

#pragma unroll
    for (int mh = 0; mh < 2; ++mh)
#pragma unroll
    for (int mi = 0; mi < 4; ++mi)
#pragma unroll
    for (int ni = 0; ni < NI; ++ni) {
        int row0 = m0 + wr * 128 + mh * 64 + mi * 16 + lg * 4;
        int col  = n0 + wc * (NI * 16) + ni * 16 + l15;
#pragma unroll
        for (int r = 0; r < 4; ++r) {
            if (OUT_BF16)
                ((u16*)Cv)[(size_t)(row0 + r) * N + col] = f2bf(acc[mh * 4 + mi][ni][r]);
            else
                ((float*)Cv)[(size_t)(row0 + r) * N + col] = acc[mh * 4 + mi][ni][r];
        }
    }
}

// ---------------- Fused RMSNorm+RoPE and V-transpose ----------------
__global__ __launch_bounds__(256) void nr_vt_kern(
    const u16* __restrict__ qkv, const float* __restrict__ qw,
    const float* __restrict__ kw, u16* __restrict__ qr, u16* __restrict__ kr,
    u16* __restrict__ vt)
{
    __shared__ u16 Ts[128][66];
    const int id = blockIdx.x, tid = threadIdx.x;
    if (id < 20480) {
        const int t = id & 2047, h = (id >> 11) * 4 + (tid >> 6);
        const int i = tid & 63;
        const size_t rowbase = (size_t)t * QKV_N;
        const u16* src; const float* w; u16* dst;
        if (h < 32) {
            src = qkv + rowbase + h * HD; w = qw;
            dst = qr + ((size_t)h * T_SEQ + t) * HD;
        } else {
            int kh = h - 32;
            src = qkv + rowbase + NQ * HD + kh * HD; w = kw;
            dst = kr + ((size_t)kh * T_SEQ + t) * HD;
        }
        float x1 = b2f(src[i]), x2 = b2f(src[i + 64]);
        float ss = x1 * x1 + x2 * x2;
#pragma unroll
        for (int d = 32; d >= 1; d >>= 1) ss += __shfl_xor(ss, d);
        float rs = rsqrtf(ss * (1.0f / 128.0f) + 1e-6f);
        x1 *= rs * w[i];
        x2 *= rs * w[i + 64];
        float ang = (float)t * exp2f((float)i * -0.20762050593567985f);
        float sn, cs;
        sincosf(ang, &sn, &cs);
        dst[i]      = f2bf(x1 * cs - x2 * sn);
        dst[i + 64] = f2bf(x2 * cs + x1 * sn);
        return;
    }
    const int id2 = id - 20480;
    const int t0 = (id2 & 31) * 64, kh = id2 >> 5;
#pragma unroll
    for (int it = 0; it < 4; ++it) {
        int slot = tid + it * 256;
        int tl = slot >> 4, dc = (slot & 15) * 8;
        s16x8 v = *(const s16x8*)&qkv[(size_t)(t0 + tl) * QKV_N + (NQ + NKV) * HD + kh * HD + dc];
#pragma unroll
        for (int e = 0; e < 8; ++e) Ts[dc + e][tl] = (u16)v[e];
    }
    __syncthreads();
#pragma unroll
    for (int it = 0; it < 4; ++it) {
        int slot = tid + it * 256;
        int d = slot >> 3, c = (slot & 7) * 8;
        s16x8 v = *(const s16x8*)&Ts[d][c];
        *(s16x8*)&vt[((size_t)kh * HD + d) * T_SEQ + t0 + c] = v;
    }
}

// ---------------- Flash attention (causal, GQA), swapped-QK^T, QBLK=128 --------
#define KS(b, r, c) Ks[(b)][((r) << 7) + ((c) ^ (((r) & 7) << 3))]
#define VS(b, r, c) Vs[(b)][((r) << 6) + ((c) ^ (((r) & 7) << 3))]
#define PS(wv, r, c) Ps[((wv) << 10) + ((r) << 6) + ((c) ^ (((r) & 7) << 3))]

__global__ __launch_bounds__(512) void attn_kern(
    const u16* __restrict__ qr, const u16* __restrict__ kr,
    const u16* __restrict__ vt, u16* __restrict__ o,
    const float* __restrict__ wo, u16* __restrict__ wo_bf)
{
    __shared__ u16 Ks[2][64 * 128];
    __shared__ u16 Vs[2][128 * 64];
    __shared__ u16 Ps[8 * 16 * 64];
    const int tid = threadIdx.x, lane = tid & 63, w = tid >> 6;
    const int lg = lane >> 4, l15 = lane & 15;
    const int fb = (int)blockIdx.y * 8 + (int)blockIdx.x;
    const int flat = xcd_swz(fb, 256);
    const int qh = flat >> 3, bx = flat & 7;
    const int kvh = qh >> 2;
    const float scale2 = 0.08838834764831845f * 1.4426950408889634f;

    const int cvbase = fb * 8192 + tid;
    int cv = 0;
    float4 cva = {}, cvb = {};

    const int krow = tid >> 4, kcol = (tid & 15) * 8;
    const int vrow = tid >> 3, vcol = (tid & 7) * 8;
    const u16* krbase = kr + (size_t)kvh * T_SEQ * HD;
    const u16* vtbase = vt + (size_t)kvh * HD * T_SEQ;

    s16x8 kst[2], vst[2];
#define LOADKV(k0_) do { \
    kst[0] = *(const s16x8*)&krbase[(size_t)((k0_) + krow) * HD + kcol]; \
    kst[1] = *(const s16x8*)&krbase[(size_t)((k0_) + krow + 32) * HD + kcol]; \
    vst[0] = *(const s16x8*)&vtbase[(size_t)(vrow) * T_SEQ + (k0_) + vcol]; \
    vst[1] = *(const s16x8*)&vtbase[(size_t)(vrow + 64) * T_SEQ + (k0_) + vcol]; \
    } while (0)
#define WRITEKV(b) do { \
    *(s16x8*)&KS((b), krow, kcol) = kst[0]; \
    *(s16x8*)&KS((b), krow + 32, kcol) = kst[1]; \
    *(s16x8*)&VS((b), vrow, vcol) = vst[0]; \
    *(s16x8*)&VS((b), vrow + 64, vcol) = vst[1]; \
    } while (0)

    for (int half = 0; half < 2; ++half) {
        const int q0 = (half == 0) ? bx * 128 : (T_SEQ - 128) - bx * 128;
        s16x8 qf[4];
        {
            const u16* qb = qr + ((size_t)qh * T_SEQ + q0 + w * 16 + l15) * HD;
#pragma unroll
            for (int dc = 0; dc < 4; ++dc) qf[dc] = *(const s16x8*)&qb[dc * 32 + lg * 8];
        }
        f32x4 oacc[8] = {};
        float mQ = -1e30f, lsQ = 0.f;

        const int ktiles = (q0 >> 6) + 2;
        LOADKV(0);
        WRITEKV(0);
        __syncthreads();
        for (int kt = 0; kt < ktiles; ++kt) {
            const int k0 = kt * 64;
            const int cur = kt & 1;
            if (kt + 1 < ktiles) LOADKV(k0 + 64);

            if (cv <= 16) {
                if (cv > 0) {
                    s16x8 o8;
                    o8[0] = (short)f2bf(cva.x); o8[1] = (short)f2bf(cva.y);
                    o8[2] = (short)f2bf(cva.z); o8[3] = (short)f2bf(cva.w);
                    o8[4] = (short)f2bf(cvb.x); o8[5] = (short)f2bf(cvb.y);
                    o8[6] = (short)f2bf(cvb.z); o8[7] = (short)f2bf(cvb.w);
                    ((s16x8*)wo_bf)[cvbase + (cv - 1) * 512] = o8;
                }
                if (cv < 16) {
                    cva = ((const float4*)wo)[2 * (cvbase + cv * 512)];
                    cvb = ((const float4*)wo)[2 * (cvbase + cv * 512) + 1];
                }
                ++cv;
            }

            f32x4 sc[4] = {};
            __builtin_amdgcn_s_setprio(1);
#pragma unroll
            for (int nc = 0; nc < 4; ++nc)
#pragma unroll
                for (int dc = 0; dc < 4; ++dc) {
                    s16x8 kf = *(const s16x8*)&KS(cur, nc * 16 + l15, dc * 32 + lg * 8);
                    sc[nc] = __builtin_amdgcn_mfma_f32_16x16x32_bf16(kf, qf[dc], sc[nc], 0, 0, 0);
                }
            __builtin_amdgcn_s_setprio(0);

            const int qg = q0 + w * 16 + l15;
            const bool needMask = (k0 + 63) > (q0 + w * 16);
            float tm = -1e30f;
#pragma unroll
            for (int nc = 0; nc < 4; ++nc)
#pragma unroll
                for (int r = 0; r < 4; ++r) {
                    float v = sc[nc][r] * scale2;
                    int kg = k0 + nc * 16 + lg * 4 + r;
                    if (needMask && kg > qg) v = -1e30f;
                    sc[nc][r] = v;
                    tm = fmaxf(tm, v);
                }
            tm = fmaxf(tm, __shfl_xor(tm, 16));
            tm = fmaxf(tm, __shfl_xor(tm, 32));

            if (__any(tm > mQ + 8.0f)) {
                float mn = fmaxf(mQ, tm);
                float alpha = exp2f(mQ - mn);
                mQ = mn;
                lsQ *= alpha;
                float aq[4];
#pragma unroll
                for (int r = 0; r < 4; ++r) aq[r] = __shfl(alpha, lg * 4 + r);
#pragma unroll
                for (int dc = 0; dc < 8; ++dc)
#pragma unroll
                    for (int r = 0; r < 4; ++r) oacc[dc][r] *= aq[r];
            }

            float ts = 0.f;
#pragma unroll
            for (int nc = 0; nc < 4; ++nc) {
                s16x4 pk;
#pragma unroll
                for (int r = 0; r < 4; ++r) {
                    float e = exp2f(sc[nc][r] - mQ);
                    ts += e;
                    pk[r] = (short)f2bf(e);
                }
                *(s16x4*)&PS(w, l15, nc * 16 + lg * 4) = pk;
            }
            ts += __shfl_xor(ts, 16);
            ts += __shfl_xor(ts, 32);
            lsQ += ts;

            __builtin_amdgcn_s_setprio(1);
#pragma unroll
            for (int kc = 0; kc < 2; ++kc) {
                s16x8 pf = *(const s16x8*)&PS(w, l15, kc * 32 + lg * 8);
#pragma unroll
                for (int dc = 0; dc < 8; ++dc) {
                    s16x8 vf = *(const s16x8*)&VS(cur, dc * 16 + l15, kc * 32 + lg * 8);
                    oacc[dc] = __builtin_amdgcn_mfma_f32_16x16x32_bf16(pf, vf, oacc[dc], 0, 0, 0);
                }
            }
            __builtin_amdgcn_s_setprio(0);

            if (kt + 1 < ktiles) WRITEKV(cur ^ 1);
            __syncthreads();
        }
        float lq[4];
#pragma unroll
        for (int r = 0; r < 4; ++r) lq[r] = __shfl(lsQ, lg * 4 + r);
#pragma unroll
        for (int r = 0; r < 4; ++r) {
            float inv = 1.0f / lq[r];
            int trow = q0 + w * 16 + lg * 4 + r;
            u16* dst = o + (size_t)trow * (NQ * HD) + qh * HD;
#pragma unroll
            for (int dc = 0; dc < 8; ++dc) dst[dc * 16 + l15] = f2bf(oacc[dc][r] * inv);
        }
    }
#undef LOADKV
#undef WRITEKV
}

extern "C" void kernel_launch(void* const* d_in, const int* in_sizes, int n_in,
                              void* d_out, int out_size, void* d_ws, size_t ws_size,
                              hipStream_t stream)
{
    const float* hs   = (const float*)d_in[0];
    const float* wqkv = (const float*)d_in[1];
    const float* qw   = (const float*)d_in[2];
    const float* kw   = (const float*)d_in[3];
    const float* wo   = (const float*)d_in[4];
    float* out = (float*)d_out;

    // workspace 92,274,688 B (88 MiB). Fully disjoint live regions per stage:
    //   gemm1: R hs_bf[0,16M) + wqkv_bf[40,88M)  -> W qkv_bf[16,40M)
    //   nr_vt: R qkv_bf[16,40M)                  -> W qr[64,80M) kr[80,84M) vt[84,88M)
    //   attn : R qr/kr/vt[64,88M) + wo(input)    -> W ob[0,16M) + wo_bf[16,48M)
    //   gemm2: R ob[0,16M) + wo_bf[16,48M)       -> W d_out
    char* ws = (char*)d_ws;
    u16* hs_bf   = (u16*)(ws);                  // [0,16M)
    u16* ob      = (u16*)(ws);                  // [0,16M)  (after gemm1)
    u16* qkv_bf  = (u16*)(ws + 16777216);       // [16,40M)
    u16* wo_bf   = (u16*)(ws + 16777216);       // [16,48M) (after nr_vt)
    u16* wqkv_bf = (u16*)(ws + 41943040);       // [40,88M)
    u16* qr      = (u16*)(ws + 67108864);       // [64,80M)
    u16* kr      = (u16*)(ws + 83886080);       // [80,84M)
    u16* vt      = (u16*)(ws + 88080384);       // [84,88M)

    // 1) convert hs + wqkv
    conv2_bf16_kern<<<2048, 256, 0, stream>>>(
        hs, hs_bf, T_SEQ * HIDDEN / 8, wqkv, wqkv_bf, QKV_N * HIDDEN / 8);
    // 2) qkv = hs @ wqkv^T  (256x192 4-sync-phase, 256 blocks = 1/CU)
    gemm_4ph<3, 1><<<dim3(QKV_N / 192, T_SEQ / 256), 512, 0, stream>>>(
        hs_bf, wqkv_bf, (void*)qkv_bf, QKV_N, HIDDEN);
    // 3) fused norm+rope / V-transpose (last reader of qkv_bf)
    nr_vt_kern<<<20736, 256, 0, stream>>>(qkv_bf, qw, kw, qr, kr, vt);
    // 4) attention with embedded wo conversion
    attn_kern<<<dim3(8, NQ), 512, 0, stream>>>(qr, kr, vt, ob, wo, wo_bf);
    // 5) out = o @ wo^T  (256x128 4-sync-phase, 256 blocks = 1/CU)
    gemm_4ph<2, 0><<<dim3(HIDDEN / 128, T_SEQ / 256), 512, 0, stream>>>(
        ob, wo_bf, (void*)out, HIDDEN, HIDDEN);
}

// Round 24
// 301.496 us; speedup vs baseline: 1.0914x; 1.0071x over previous
//
#include <hip/hip_runtime.h>
#include <hip/hip_bf16.h>

typedef float f32x4 __attribute__((ext_vector_type(4)));
typedef short s16x8 __attribute__((ext_vector_type(8)));
typedef short s16x4 __attribute__((ext_vector_type(4)));
typedef unsigned short u16;

#define HIDDEN 4096
#define NQ 32
#define NKV 8
#define HD 128
#define T_SEQ 2048
#define QKV_N ((NQ + 2 * NKV) * HD)   // 6144

__device__ __forceinline__ u16 f2bf(float f) {
    union { float f; unsigned u; } v; v.f = f;
    unsigned r = v.u + 0x7FFFu + ((v.u >> 16) & 1u);
    return (u16)(r >> 16);
}
__device__ __forceinline__ float b2f(u16 h) {
    union { unsigned u; float f; } v; v.u = ((unsigned)h) << 16; return v.f;
}
__device__ __forceinline__ void gload_lds16(const u16* g, u16* l) {
    __builtin_amdgcn_global_load_lds(
        (const __attribute__((address_space(1))) unsigned int*)g,
        (__attribute__((address_space(3))) unsigned int*)l,
        16, 0, 0);
}
// bijective XCD remap (nwg % 8 == 0): contiguous chunk per XCD
__device__ __forceinline__ int xcd_swz(int flat, int nwg) {
    return (flat & 7) * (nwg >> 3) + (flat >> 3);
}

// ---------------- f32 -> bf16 bulk convert (two segments) ----------------
__device__ __forceinline__ void conv8(const float* src, u16* dst, int i) {
    const float4 a = ((const float4*)src)[2 * i];
    const float4 b = ((const float4*)src)[2 * i + 1];
    s16x8 o;
    o[0] = (short)f2bf(a.x); o[1] = (short)f2bf(a.y);
    o[2] = (short)f2bf(a.z); o[3] = (short)f2bf(a.w);
    o[4] = (short)f2bf(b.x); o[5] = (short)f2bf(b.y);
    o[6] = (short)f2bf(b.z); o[7] = (short)f2bf(b.w);
    ((s16x8*)dst)[i] = o;
}
__global__ __launch_bounds__(256) void conv2_bf16_kern(
    const float* __restrict__ s1, u16* __restrict__ d1, int n1,
    const float* __restrict__ s2, u16* __restrict__ d2, int n2)
{
    for (int i = blockIdx.x * 256 + threadIdx.x; i < n1 + n2; i += gridDim.x * 256) {
        if (i < n1) conv8(s1, d1, i);
        else        conv8(s2, d2, i - n1);
    }
}

// ============ gemm1: 4-sync-phase, tile 256x192, BK=64 (r22-proven) ========
// 512 thr = 8 waves (2M x 4N); acc[8][3]. 2 compute phases/tile, 4 barriers.
// Slot-parity invariant (tile tau in slot tau&1):
//   ph1(mh0): read af+bq; stage A[s^1]{c1,c3}(t+1) + B[s^1]{c0..c2}(t+1)
//   ph2(mh1): read af{c1,c3}, reuse bq; stage A[s]{c0,c2}(t+2)
//   tile-end: vmcnt(2); tails vmcnt(0). Prologue: 9 loads, vmcnt(2).
__global__ __launch_bounds__(512) void gemm1_4ph(
    const u16* __restrict__ A, const u16* __restrict__ B,
    u16* __restrict__ C, int N, int K)
{
    __shared__ u16 As[2][256 * 64];
    __shared__ u16 Bs[2][192 * 64];
    const int tid = threadIdx.x, lane = tid & 63, wid = tid >> 6;
    const int wr = wid >> 2, wc = wid & 3;
    const int lg = lane >> 4, l15 = lane & 15;
    const int m0 = blockIdx.y * 256, n0 = blockIdx.x * 192;
    const int nk = K >> 6;
    const int r8 = lane >> 3;
    const int csw = ((lane & 7) ^ r8) * 8;

    f32x4 acc[8][3] = {};
    s16x8 af[4][2], bq[3][2];

    auto stageA = [&](int sl, int c, int kt) {
        gload_lds16(&A[(size_t)(m0 + c * 64 + wid * 8 + r8) * K + kt * 64 + csw],
                    &As[sl][(c * 64 + wid * 8) * 64]);
    };
    auto stageB = [&](int sl, int c, int kt) {
        gload_lds16(&B[(size_t)(n0 + c * 64 + wid * 8 + r8) * K + kt * 64 + csw],
                    &Bs[sl][(c * 64 + wid * 8) * 64]);
    };
    auto ldA2 = [&](int s_, int mh_) {
#pragma unroll
        for (int mi = 0; mi < 4; ++mi)
#pragma unroll
            for (int kh = 0; kh < 2; ++kh)
                af[mi][kh] = *(const s16x8*)&As[s_][
                    ((wr * 128 + mh_ * 64 + mi * 16 + l15) << 6) +
                    (((lg + kh * 4) ^ (l15 & 7)) << 3)];
    };
    auto ldB2 = [&](int s_) {
#pragma unroll
        for (int ni = 0; ni < 3; ++ni)
#pragma unroll
            for (int kh = 0; kh < 2; ++kh)
                bq[ni][kh] = *(const s16x8*)&Bs[s_][
                    ((wc * 48 + ni * 16 + l15) << 6) +
                    (((lg + kh * 4) ^ (l15 & 7)) << 3)];
    };
    auto mm2 = [&](int mh_) {
        __builtin_amdgcn_s_setprio(1);
#pragma unroll
        for (int mi = 0; mi < 4; ++mi)
#pragma unroll
            for (int ni = 0; ni < 3; ++ni)
#pragma unroll
                for (int kh = 0; kh < 2; ++kh)
                    acc[mh_ * 4 + mi][ni] =
                        __builtin_amdgcn_mfma_f32_16x16x32_bf16(
                            af[mi][kh], bq[ni][kh], acc[mh_ * 4 + mi][ni], 0, 0, 0);
        __builtin_amdgcn_s_setprio(0);
    };
#define FENCE asm volatile("" ::: "memory");

    stageA(0, 0, 0); stageA(0, 1, 0); stageA(0, 2, 0); stageA(0, 3, 0);
    stageB(0, 0, 0); stageB(0, 1, 0); stageB(0, 2, 0);
    stageA(1, 0, 1); stageA(1, 2, 1);
    asm volatile("s_waitcnt vmcnt(2)" ::: "memory");
    __builtin_amdgcn_s_barrier();

    for (int t = 0; t < nk; ++t) {
        const int s = t & 1;
        ldA2(s, 0); ldB2(s);
        if (t + 1 < nk) {
            stageA(s ^ 1, 1, t + 1); stageA(s ^ 1, 3, t + 1);
            stageB(s ^ 1, 0, t + 1); stageB(s ^ 1, 1, t + 1); stageB(s ^ 1, 2, t + 1);
        }
        FENCE
        __builtin_amdgcn_s_barrier();
        mm2(0);
        FENCE
        __builtin_amdgcn_s_barrier();
        ldA2(s, 1);
        if (t + 2 < nk) { stageA(s, 0, t + 2); stageA(s, 2, t + 2); }
        FENCE
        __builtin_amdgcn_s_barrier();
        mm2(1);
        if (t + 2 < nk) asm volatile("s_waitcnt vmcnt(2)" ::: "memory");
        else            asm volatile("s_waitcnt vmcnt(0)" ::: "memory");
        FENCE
        __builtin_amdgcn_s_barrier();
    }

#pragma unroll
    for (int mh = 0; mh < 2; ++mh)
#pragma unroll
    for (int mi = 0; mi < 4; ++mi)
#pragma unroll
    for (int ni = 0; ni < 3; ++ni) {
        int row0 = m0 + wr * 128 + mh * 64 + mi * 16 + lg * 4;
        int col  = n0 + wc * 48 + ni * 16 + l15;
#pragma unroll
        for (int r = 0; r < 4; ++r)
            C[(size_t)(row0 + r) * N + col] = f2bf(acc[mh * 4 + mi][ni][r]);
    }
}

// ============ gemm2: 2-sync-phase, tile 256x128, BK=64, 3-slot LDS =========
// 256 blocks (32x8) = 1/CU. LDS 144 KB (3-slot rotation buys vmcnt headroom
// at 2 syncs: stage t+2 -> slot (t+2)%3 = slot(t-1), whose reads finished at
// tile t-1 before its trailing barrier). Per tile: 20 ds_read + 6 gload ->
// barrier -> 32 MFMA -> vmcnt(6) (drains t+1, leaves t+2) -> barrier.
// Tails vmcnt(0). Prologue: t0+t1 (12 loads), vmcnt(6).
__global__ __launch_bounds__(512) void gemm2_2ph(
    const u16* __restrict__ A, const u16* __restrict__ B,
    float* __restrict__ C, int N, int K)
{
    __shared__ u16 As[3][256 * 64];
    __shared__ u16 Bs[3][128 * 64];
    const int tid = threadIdx.x, lane = tid & 63, wid = tid >> 6;
    const int wr = wid >> 2, wc = wid & 3;
    const int lg = lane >> 4, l15 = lane & 15;
    const int m0 = blockIdx.y * 256, n0 = blockIdx.x * 128;
    const int nk = K >> 6;
    const int r8 = lane >> 3;
    const int csw = ((lane & 7) ^ r8) * 8;

    f32x4 acc[8][2] = {};
    s16x8 af[8][2], bq[2][2];

    auto stageAll = [&](int sl, int kt) {
#pragma unroll
        for (int c = 0; c < 4; ++c)
            gload_lds16(&A[(size_t)(m0 + c * 64 + wid * 8 + r8) * K + kt * 64 + csw],
                        &As[sl][(c * 64 + wid * 8) * 64]);
#pragma unroll
        for (int c = 0; c < 2; ++c)
            gload_lds16(&B[(size_t)(n0 + c * 64 + wid * 8 + r8) * K + kt * 64 + csw],
                        &Bs[sl][(c * 64 + wid * 8) * 64]);
    };
    auto ldAll = [&](int s_) {
#pragma unroll
        for (int mi = 0; mi < 8; ++mi)
#pragma unroll
            for (int kh = 0; kh < 2; ++kh)
                af[mi][kh] = *(const s16x8*)&As[s_][
                    ((wr * 128 + mi * 16 + l15) << 6) +
                    (((lg + kh * 4) ^ (l15 & 7)) << 3)];
#pragma unroll
        for (int ni = 0; ni < 2; ++ni)
#pragma unroll
            for (int kh = 0; kh < 2; ++kh)
                bq[ni][kh] = *(const s16x8*)&Bs[s_][
                    ((wc * 32 + ni * 16 + l15) << 6) +
                    (((lg + kh * 4) ^ (l15 & 7)) << 3)];
    };
    auto mmAll = [&]() {
        __builtin_amdgcn_s_setprio(1);
#pragma unroll
        for (int mi = 0; mi < 8; ++mi)
#pragma unroll
            for (int ni = 0; ni < 2; ++ni)
#pragma unroll
                for (int kh = 0; kh < 2; ++kh)
                    acc[mi][ni] = __builtin_amdgcn_mfma_f32_16x16x32_bf16(
                        af[mi][kh], bq[ni][kh], acc[mi][ni], 0, 0, 0);
        __builtin_amdgcn_s_setprio(0);
    };
#define FENCE asm volatile("" ::: "memory");

    stageAll(0, 0);
    stageAll(1, 1);
    asm volatile("s_waitcnt vmcnt(6)" ::: "memory");   // tile 0 landed
    __builtin_amdgcn_s_barrier();

    int s = 0;
    for (int t = 0; t < nk; ++t) {
        ldAll(s);
        if (t + 2 < nk) {
            int s2 = s + 2; if (s2 >= 3) s2 -= 3;
            stageAll(s2, t + 2);
        }
        FENCE
        __builtin_amdgcn_s_barrier();
        mmAll();
        if (t + 2 < nk) asm volatile("s_waitcnt vmcnt(6)" ::: "memory");
        else            asm volatile("s_waitcnt vmcnt(0)" ::: "memory");
        FENCE
        __builtin_amdgcn_s_barrier();
        if (++s >= 3) s -= 3;
    }
#undef FENCE

#pragma unroll
    for (int mi = 0; mi < 8; ++mi)
#pragma unroll
    for (int ni = 0; ni < 2; ++ni) {
        int row0 = m0 + wr * 128 + mi * 16 + lg * 4;
        int col  = n0 + wc * 32 + ni * 16 + l15;
#pragma unroll
        for (int r = 0; r < 4; ++r)
            C[(size_t)(row0 + r) * N + col] = acc[mi][ni][r];
    }
}

// ---------------- Fused RMSNorm+RoPE and V-transpose ----------------
__global__ __launch_bounds__(256) void nr_vt_kern(
    const u16* __restrict__ qkv, const float* __restrict__ qw,
    const float* __restrict__ kw, u16* __restrict__ qr, u16* __restrict__ kr,
    u16* __restrict__ vt)
{
    __shared__ u16 Ts[128][66];
    const int id = blockIdx.x, tid = threadIdx.x;
    if (id < 20480) {
        const int t = id & 2047, h = (id >> 11) * 4 + (tid >> 6);
        const int i = tid & 63;
        const size_t rowbase = (size_t)t * QKV_N;
        const u16* src; const float* w; u16* dst;
        if (h < 32) {
            src = qkv + rowbase + h * HD; w = qw;
            dst = qr + ((size_t)h * T_SEQ + t) * HD;
        } else {
            int kh = h - 32;
            src = qkv + rowbase + NQ * HD + kh * HD; w = kw;
            dst = kr + ((size_t)kh * T_SEQ + t) * HD;
        }
        float x1 = b2f(src[i]), x2 = b2f(src[i + 64]);
        float ss = x1 * x1 + x2 * x2;
#pragma unroll
        for (int d = 32; d >= 1; d >>= 1) ss += __shfl_xor(ss, d);
        float rs = rsqrtf(ss * (1.0f / 128.0f) + 1e-6f);
        x1 *= rs * w[i];
        x2 *= rs * w[i + 64];
        float ang = (float)t * exp2f((float)i * -0.20762050593567985f);
        float sn, cs;
        sincosf(ang, &sn, &cs);
        dst[i]      = f2bf(x1 * cs - x2 * sn);
        dst[i + 64] = f2bf(x2 * cs + x1 * sn);
        return;
    }
    const int id2 = id - 20480;
    const int t0 = (id2 & 31) * 64, kh = id2 >> 5;
#pragma unroll
    for (int it = 0; it < 4; ++it) {
        int slot = tid + it * 256;
        int tl = slot >> 4, dc = (slot & 15) * 8;
        s16x8 v = *(const s16x8*)&qkv[(size_t)(t0 + tl) * QKV_N + (NQ + NKV) * HD + kh * HD + dc];
#pragma unroll
        for (int e = 0; e < 8; ++e) Ts[dc + e][tl] = (u16)v[e];
    }
    __syncthreads();
#pragma unroll
    for (int it = 0; it < 4; ++it) {
        int slot = tid + it * 256;
        int d = slot >> 3, c = (slot & 7) * 8;
        s16x8 v = *(const s16x8*)&Ts[d][c];
        *(s16x8*)&vt[((size_t)kh * HD + d) * T_SEQ + t0 + c] = v;
    }
}

// ---------------- Flash attention (causal, GQA), swapped-QK^T, QBLK=128 --------
#define KS(b, r, c) Ks[(b)][((r) << 7) + ((c) ^ (((r) & 7) << 3))]
#define VS(b, r, c) Vs[(b)][((r) << 6) + ((c) ^ (((r) & 7) << 3))]
#define PS(wv, r, c) Ps[((wv) << 10) + ((r) << 6) + ((c) ^ (((r) & 7) << 3))]

__global__ __launch_bounds__(512) void attn_kern(
    const u16* __restrict__ qr, const u16* __restrict__ kr,
    const u16* __restrict__ vt, u16* __restrict__ o,
    const float* __restrict__ wo, u16* __restrict__ wo_bf)
{
    __shared__ u16 Ks[2][64 * 128];
    __shared__ u16 Vs[2][128 * 64];
    __shared__ u16 Ps[8 * 16 * 64];
    const int tid = threadIdx.x, lane = tid & 63, w = tid >> 6;
    const int lg = lane >> 4, l15 = lane & 15;
    const int fb = (int)blockIdx.y * 8 + (int)blockIdx.x;
    const int flat = xcd_swz(fb, 256);
    const int qh = flat >> 3, bx = flat & 7;
    const int kvh = qh >> 2;
    const float scale2 = 0.08838834764831845f * 1.4426950408889634f;

    const int cvbase = fb * 8192 + tid;
    int cv = 0;
    float4 cva = {}, cvb = {};

    const int krow = tid >> 4, kcol = (tid & 15) * 8;
    const int vrow = tid >> 3, vcol = (tid & 7) * 8;
    const u16* krbase = kr + (size_t)kvh * T_SEQ * HD;
    const u16* vtbase = vt + (size_t)kvh * HD * T_SEQ;

    s16x8 kst[2], vst[2];
#define LOADKV(k0_) do { \
    kst[0] = *(const s16x8*)&krbase[(size_t)((k0_) + krow) * HD + kcol]; \
    kst[1] = *(const s16x8*)&krbase[(size_t)((k0_) + krow + 32) * HD + kcol]; \
    vst[0] = *(const s16x8*)&vtbase[(size_t)(vrow) * T_SEQ + (k0_) + vcol]; \
    vst[1] = *(const s16x8*)&vtbase[(size_t)(vrow + 64) * T_SEQ + (k0_) + vcol]; \
    } while (0)
#define WRITEKV(b) do { \
    *(s16x8*)&KS((b), krow, kcol) = kst[0]; \
    *(s16x8*)&KS((b), krow + 32, kcol) = kst[1]; \
    *(s16x8*)&VS((b), vrow, vcol) = vst[0]; \
    *(s16x8*)&VS((b), vrow + 64, vcol) = vst[1]; \
    } while (0)

    for (int half = 0; half < 2; ++half) {
        const int q0 = (half == 0) ? bx * 128 : (T_SEQ - 128) - bx * 128;
        s16x8 qf[4];
        {
            const u16* qb = qr + ((size_t)qh * T_SEQ + q0 + w * 16 + l15) * HD;
#pragma unroll
            for (int dc = 0; dc < 4; ++dc) qf[dc] = *(const s16x8*)&qb[dc * 32 + lg * 8];
        }
        f32x4 oacc[8] = {};
        float mQ = -1e30f, lsQ = 0.f;

        const int ktiles = (q0 >> 6) + 2;
        LOADKV(0);
        WRITEKV(0);
        __syncthreads();
        for (int kt = 0; kt < ktiles; ++kt) {
            const int k0 = kt * 64;
            const int cur = kt & 1;
            if (kt + 1 < ktiles) LOADKV(k0 + 64);

            if (cv <= 16) {
                if (cv > 0) {
                    s16x8 o8;
                    o8[0] = (short)f2bf(cva.x); o8[1] = (short)f2bf(cva.y);
                    o8[2] = (short)f2bf(cva.z); o8[3] = (short)f2bf(cva.w);
                    o8[4] = (short)f2bf(cvb.x); o8[5] = (short)f2bf(cvb.y);
                    o8[6] = (short)f2bf(cvb.z); o8[7] = (short)f2bf(cvb.w);
                    ((s16x8*)wo_bf)[cvbase + (cv - 1) * 512] = o8;
                }
                if (cv < 16) {
                    cva = ((const float4*)wo)[2 * (cvbase + cv * 512)];
                    cvb = ((const float4*)wo)[2 * (cvbase + cv * 512) + 1];
                }
                ++cv;
            }

            f32x4 sc[4] = {};
            __builtin_amdgcn_s_setprio(1);
#pragma unroll
            for (int nc = 0; nc < 4; ++nc)
#pragma unroll
                for (int dc = 0; dc < 4; ++dc) {
                    s16x8 kf = *(const s16x8*)&KS(cur, nc * 16 + l15, dc * 32 + lg * 8);
                    sc[nc] = __builtin_amdgcn_mfma_f32_16x16x32_bf16(kf, qf[dc], sc[nc], 0, 0, 0);
                }
            __builtin_amdgcn_s_setprio(0);

            const int qg = q0 + w * 16 + l15;
            const bool needMask = (k0 + 63) > (q0 + w * 16);
            float tm = -1e30f;
#pragma unroll
            for (int nc = 0; nc < 4; ++nc)
#pragma unroll
                for (int r = 0; r < 4; ++r) {
                    float v = sc[nc][r] * scale2;
                    int kg = k0 + nc * 16 + lg * 4 + r;
                    if (needMask && kg > qg) v = -1e30f;
                    sc[nc][r] = v;
                    tm = fmaxf(tm, v);
                }
            tm = fmaxf(tm, __shfl_xor(tm, 16));
            tm = fmaxf(tm, __shfl_xor(tm, 32));

            if (__any(tm > mQ + 8.0f)) {
                float mn = fmaxf(mQ, tm);
                float alpha = exp2f(mQ - mn);
                mQ = mn;
                lsQ *= alpha;
                float aq[4];
#pragma unroll
                for (int r = 0; r < 4; ++r) aq[r] = __shfl(alpha, lg * 4 + r);
#pragma unroll
                for (int dc = 0; dc < 8; ++dc)
#pragma unroll
                    for (int r = 0; r < 4; ++r) oacc[dc][r] *= aq[r];
            }

            float ts = 0.f;
#pragma unroll
            for (int nc = 0; nc < 4; ++nc) {
                s16x4 pk;
#pragma unroll
                for (int r = 0; r < 4; ++r) {
                    float e = exp2f(sc[nc][r] - mQ);
                    ts += e;
                    pk[r] = (short)f2bf(e);
                }
                *(s16x4*)&PS(w, l15, nc * 16 + lg * 4) = pk;
            }
            ts += __shfl_xor(ts, 16);
            ts += __shfl_xor(ts, 32);
            lsQ += ts;

            __builtin_amdgcn_s_setprio(1);
#pragma unroll
            for (int kc = 0; kc < 2; ++kc) {
                s16x8 pf = *(const s16x8*)&PS(w, l15, kc * 32 + lg * 8);
#pragma unroll
                for (int dc = 0; dc < 8; ++dc) {
                    s16x8 vf = *(const s16x8*)&VS(cur, dc * 16 + l15, kc * 32 + lg * 8);
                    oacc[dc] = __builtin_amdgcn_mfma_f32_16x16x32_bf16(pf, vf, oacc[dc], 0, 0, 0);
                }
            }
            __builtin_amdgcn_s_setprio(0);

            if (kt + 1 < ktiles) WRITEKV(cur ^ 1);
            __syncthreads();
        }
        float lq[4];
#pragma unroll
        for (int r = 0; r < 4; ++r) lq[r] = __shfl(lsQ, lg * 4 + r);
#pragma unroll
        for (int r = 0; r < 4; ++r) {
            float inv = 1.0f / lq[r];
            int trow = q0 + w * 16 + lg * 4 + r;
            u16* dst = o + (size_t)trow * (NQ * HD) + qh * HD;
#pragma unroll
            for (int dc = 0; dc < 8; ++dc) dst[dc * 16 + l15] = f2bf(oacc[dc][r] * inv);
        }
    }
#undef LOADKV
#undef WRITEKV
}

extern "C" void kernel_launch(void* const* d_in, const int* in_sizes, int n_in,
                              void* d_out, int out_size, void* d_ws, size_t ws_size,
                              hipStream_t stream)
{
    const float* hs   = (const float*)d_in[0];
    const float* wqkv = (const float*)d_in[1];
    const float* qw   = (const float*)d_in[2];
    const float* kw   = (const float*)d_in[3];
    const float* wo   = (const float*)d_in[4];
    float* out = (float*)d_out;

    // workspace 92,274,688 B (88 MiB). Fully disjoint live regions per stage:
    //   gemm1: R hs_bf[0,16M) + wqkv_bf[40,88M)  -> W qkv_bf[16,40M)
    //   nr_vt: R qkv_bf[16,40M)                  -> W qr[64,80M) kr[80,84M) vt[84,88M)
    //   attn : R qr/kr/vt[64,88M) + wo(input)    -> W ob[0,16M) + wo_bf[16,48M)
    //   gemm2: R ob[0,16M) + wo_bf[16,48M)       -> W d_out
    char* ws = (char*)d_ws;
    u16* hs_bf   = (u16*)(ws);                  // [0,16M)
    u16* ob      = (u16*)(ws);                  // [0,16M)  (after gemm1)
    u16* qkv_bf  = (u16*)(ws + 16777216);       // [16,40M)
    u16* wo_bf   = (u16*)(ws + 16777216);       // [16,48M) (after nr_vt)
    u16* wqkv_bf = (u16*)(ws + 41943040);       // [40,88M)
    u16* qr      = (u16*)(ws + 67108864);       // [64,80M)
    u16* kr      = (u16*)(ws + 83886080);       // [80,84M)
    u16* vt      = (u16*)(ws + 88080384);       // [84,88M)

    // 1) convert hs + wqkv
    conv2_bf16_kern<<<2048, 256, 0, stream>>>(
        hs, hs_bf, T_SEQ * HIDDEN / 8, wqkv, wqkv_bf, QKV_N * HIDDEN / 8);
    // 2) qkv = hs @ wqkv^T  (256x192 4-sync-phase, 256 blocks = 1/CU)
    gemm1_4ph<<<dim3(QKV_N / 192, T_SEQ / 256), 512, 0, stream>>>(
        hs_bf, wqkv_bf, qkv_bf, QKV_N, HIDDEN);
    // 3) fused norm+rope / V-transpose (last reader of qkv_bf)
    nr_vt_kern<<<20736, 256, 0, stream>>>(qkv_bf, qw, kw, qr, kr, vt);
    // 4) attention with embedded wo conversion
    attn_kern<<<dim3(8, NQ), 512, 0, stream>>>(qr, kr, vt, ob, wo, wo_bf);
    // 5) out = o @ wo^T  (256x128 2-sync-phase 3-slot, 256 blocks = 1/CU)
    gemm2_2ph<<<dim3(HIDDEN / 128, T_SEQ / 256), 512, 0, stream>>>(
        ob, wo_bf, out, HIDDEN, HIDDEN);
}

// Round 25
// 299.384 us; speedup vs baseline: 1.0991x; 1.0071x over previous
//
#include <hip/hip_runtime.h>
#include <hip/hip_bf16.h>

typedef float f32x4 __attribute__((ext_vector_type(4)));
typedef short s16x8 __attribute__((ext_vector_type(8)));
typedef short s16x4 __attribute__((ext_vector_type(4)));
typedef unsigned short u16;

#define HIDDEN 4096
#define NQ 32
#define NKV 8
#define HD 128
#define T_SEQ 2048
#define QKV_N ((NQ + 2 * NKV) * HD)   // 6144

__device__ __forceinline__ u16 f2bf(float f) {
    union { float f; unsigned u; } v; v.f = f;
    unsigned r = v.u + 0x7FFFu + ((v.u >> 16) & 1u);
    return (u16)(r >> 16);
}
__device__ __forceinline__ float b2f(u16 h) {
    union { unsigned u; float f; } v; v.u = ((unsigned)h) << 16; return v.f;
}
__device__ __forceinline__ void gload_lds16(const u16* g, u16* l) {
    __builtin_amdgcn_global_load_lds(
        (const __attribute__((address_space(1))) unsigned int*)g,
        (__attribute__((address_space(3))) unsigned int*)l,
        16, 0, 0);
}
// bijective XCD remap (nwg % 8 == 0): contiguous chunk per XCD
__device__ __forceinline__ int xcd_swz(int flat, int nwg) {
    return (flat & 7) * (nwg >> 3) + (flat >> 3);
}

// ---------------- f32 -> bf16 bulk convert (two segments) ----------------
__device__ __forceinline__ void conv8(const float* src, u16* dst, int i) {
    const float4 a = ((const float4*)src)[2 * i];
    const float4 b = ((const float4*)src)[2 * i + 1];
    s16x8 o;
    o[0] = (short)f2bf(a.x); o[1] = (short)f2bf(a.y);
    o[2] = (short)f2bf(a.z); o[3] = (short)f2bf(a.w);
    o[4] = (short)f2bf(b.x); o[5] = (short)f2bf(b.y);
    o[6] = (short)f2bf(b.z); o[7] = (short)f2bf(b.w);
    ((s16x8*)dst)[i] = o;
}
__global__ __launch_bounds__(256) void conv2_bf16_kern(
    const float* __restrict__ s1, u16* __restrict__ d1, int n1,
    const float* __restrict__ s2, u16* __restrict__ d2, int n2)
{
    for (int i = blockIdx.x * 256 + threadIdx.x; i < n1 + n2; i += gridDim.x * 256) {
        if (i < n1) conv8(s1, d1, i);
        else        conv8(s2, d2, i - n1);
    }
}

// ============ gemm1: 2-sync-phase, tile 256x192, BK=64, mixed slots ========
// 256 blocks (32x8) = 1/CU. A 3-slot (96KB) + B 2-slot (48KB) = 144KB LDS.
// Per tile t (s3=t%3, s2=t&1): ldAll (af[8][2]+bq[3][2], 22 ds_read) ||
// stage B(t+1)->Bs[s2^1] FIRST then A(t+2)->As[(t+2)%3] -> barrier ->
// 48 MFMA -> vmcnt(4) -> barrier.
// vmcnt: end-of-tile queue = [A(t+1)x4, B(t+1)x3, A(t+2)x4]; vmcnt(4)
// completes exactly A(t+1)+B(t+1) (B-before-A issue order makes the count
// work); tails vmcnt(0). Safety: B slot s2^1 last read tile t-1 (done before
// its trailing barrier via MFMA consumption); A slot (t+2)%3 = (t-1)%3 ditto.
// B's 1-tile issue->consume gap (~2800cy) >> HBM latency (~900cy).
// Prologue: A(0),B(0),A(1) (11 loads), vmcnt(4).
__global__ __launch_bounds__(512) void gemm1_2ph(
    const u16* __restrict__ A, const u16* __restrict__ B,
    u16* __restrict__ C, int N, int K)
{
    __shared__ u16 As[3][256 * 64];
    __shared__ u16 Bs[2][192 * 64];
    const int tid = threadIdx.x, lane = tid & 63, wid = tid >> 6;
    const int wr = wid >> 2, wc = wid & 3;
    const int lg = lane >> 4, l15 = lane & 15;
    const int m0 = blockIdx.y * 256, n0 = blockIdx.x * 192;
    const int nk = K >> 6;
    const int r8 = lane >> 3;
    const int csw = ((lane & 7) ^ r8) * 8;

    f32x4 acc[8][3] = {};
    s16x8 af[8][2], bq[3][2];

    auto stageA = [&](int sl, int kt) {
#pragma unroll
        for (int c = 0; c < 4; ++c)
            gload_lds16(&A[(size_t)(m0 + c * 64 + wid * 8 + r8) * K + kt * 64 + csw],
                        &As[sl][(c * 64 + wid * 8) * 64]);
    };
    auto stageB = [&](int sl, int kt) {
#pragma unroll
        for (int c = 0; c < 3; ++c)
            gload_lds16(&B[(size_t)(n0 + c * 64 + wid * 8 + r8) * K + kt * 64 + csw],
                        &Bs[sl][(c * 64 + wid * 8) * 64]);
    };
    auto ldAll = [&](int s3_, int s2_) {
#pragma unroll
        for (int mi = 0; mi < 8; ++mi)
#pragma unroll
            for (int kh = 0; kh < 2; ++kh)
                af[mi][kh] = *(const s16x8*)&As[s3_][
                    ((wr * 128 + mi * 16 + l15) << 6) +
                    (((lg + kh * 4) ^ (l15 & 7)) << 3)];
#pragma unroll
        for (int ni = 0; ni < 3; ++ni)
#pragma unroll
            for (int kh = 0; kh < 2; ++kh)
                bq[ni][kh] = *(const s16x8*)&Bs[s2_][
                    ((wc * 48 + ni * 16 + l15) << 6) +
                    (((lg + kh * 4) ^ (l15 & 7)) << 3)];
    };
    auto mmAll = [&]() {
        __builtin_amdgcn_s_setprio(1);
#pragma unroll
        for (int mi = 0; mi < 8; ++mi)
#pragma unroll
            for (int ni = 0; ni < 3; ++ni)
#pragma unroll
                for (int kh = 0; kh < 2; ++kh)
                    acc[mi][ni] = __builtin_amdgcn_mfma_f32_16x16x32_bf16(
                        af[mi][kh], bq[ni][kh], acc[mi][ni], 0, 0, 0);
        __builtin_amdgcn_s_setprio(0);
    };
#define FENCE asm volatile("" ::: "memory");

    // prologue: A(0)->s3=0, B(0)->s2=0, A(1)->s3=1; drain A0,B0 (leave A1)
    stageA(0, 0);
    stageB(0, 0);
    stageA(1, 1);
    asm volatile("s_waitcnt vmcnt(4)" ::: "memory");
    __builtin_amdgcn_s_barrier();

    int s3 = 0;
    for (int t = 0; t < nk; ++t) {
        const int s2 = t & 1;
        ldAll(s3, s2);
        if (t + 1 < nk) stageB(s2 ^ 1, t + 1);       // B first (vmcnt count)
        if (t + 2 < nk) {
            int sn = s3 + 2; if (sn >= 3) sn -= 3;
            stageA(sn, t + 2);
        }
        FENCE
        __builtin_amdgcn_s_barrier();
        mmAll();
        if (t + 2 < nk) asm volatile("s_waitcnt vmcnt(4)" ::: "memory");
        else            asm volatile("s_waitcnt vmcnt(0)" ::: "memory");
        FENCE
        __builtin_amdgcn_s_barrier();
        if (++s3 >= 3) s3 -= 3;
    }
#undef FENCE

#pragma unroll
    for (int mi = 0; mi < 8; ++mi)
#pragma unroll
    for (int ni = 0; ni < 3; ++ni) {
        int row0 = m0 + wr * 128 + mi * 16 + lg * 4;
        int col  = n0 + wc * 48 + ni * 16 + l15;
#pragma unroll
        for (int r = 0; r < 4; ++r)
            C[(size_t)(row0 + r) * N + col] = f2bf(acc[mi][ni][r]);
    }
}

// ============ gemm2: 2-sync-phase, tile 256x128, BK=64, 3-slot LDS =========
// 256 blocks (32x8) = 1/CU. LDS 144 KB. Per tile: 20 ds_read + 6 gload ->
// barrier -> 32 MFMA -> vmcnt(6) -> barrier. Tails vmcnt(0).
__global__ __launch_bounds__(512) void gemm2_2ph(
    const u16* __restrict__ A, const u16* __restrict__ B,
    float* __restrict__ C, int N, int K)
{
    __shared__ u16 As[3][256 * 64];
    __shared__ u16 Bs[3][128 * 64];
    const int tid = threadIdx.x, lane = tid & 63, wid = tid >> 6;
    const int wr = wid >> 2, wc = wid & 3;
    const int lg = lane >> 4, l15 = lane & 15;
    const int m0 = blockIdx.y * 256, n0 = blockIdx.x * 128;
    const int nk = K >> 6;
    const int r8 = lane >> 3;
    const int csw = ((lane & 7) ^ r8) * 8;

    f32x4 acc[8][2] = {};
    s16x8 af[8][2], bq[2][2];

    auto stageAll = [&](int sl, int kt) {
#pragma unroll
        for (int c = 0; c < 4; ++c)
            gload_lds16(&A[(size_t)(m0 + c * 64 + wid * 8 + r8) * K + kt * 64 + csw],
                        &As[sl][(c * 64 + wid * 8) * 64]);
#pragma unroll
        for (int c = 0; c < 2; ++c)
            gload_lds16(&B[(size_t)(n0 + c * 64 + wid * 8 + r8) * K + kt * 64 + csw],
                        &Bs[sl][(c * 64 + wid * 8) * 64]);
    };
    auto ldAll = [&](int s_) {
#pragma unroll
        for (int mi = 0; mi < 8; ++mi)
#pragma unroll
            for (int kh = 0; kh < 2; ++kh)
                af[mi][kh] = *(const s16x8*)&As[s_][
                    ((wr * 128 + mi * 16 + l15) << 6) +
                    (((lg + kh * 4) ^ (l15 & 7)) << 3)];
#pragma unroll
        for (int ni = 0; ni < 2; ++ni)
#pragma unroll
            for (int kh = 0; kh < 2; ++kh)
                bq[ni][kh] = *(const s16x8*)&Bs[s_][
                    ((wc * 32 + ni * 16 + l15) << 6) +
                    (((lg + kh * 4) ^ (l15 & 7)) << 3)];
    };
    auto mmAll = [&]() {
        __builtin_amdgcn_s_setprio(1);
#pragma unroll
        for (int mi = 0; mi < 8; ++mi)
#pragma unroll
            for (int ni = 0; ni < 2; ++ni)
#pragma unroll
                for (int kh = 0; kh < 2; ++kh)
                    acc[mi][ni] = __builtin_amdgcn_mfma_f32_16x16x32_bf16(
                        af[mi][kh], bq[ni][kh], acc[mi][ni], 0, 0, 0);
        __builtin_amdgcn_s_setprio(0);
    };
#define FENCE asm volatile("" ::: "memory");

    stageAll(0, 0);
    stageAll(1, 1);
    asm volatile("s_waitcnt vmcnt(6)" ::: "memory");   // tile 0 landed
    __builtin_amdgcn_s_barrier();

    int s = 0;
    for (int t = 0; t < nk; ++t) {
        ldAll(s);
        if (t + 2 < nk) {
            int s2 = s + 2; if (s2 >= 3) s2 -= 3;
            stageAll(s2, t + 2);
        }
        FENCE
        __builtin_amdgcn_s_barrier();
        mmAll();
        if (t + 2 < nk) asm volatile("s_waitcnt vmcnt(6)" ::: "memory");
        else            asm volatile("s_waitcnt vmcnt(0)" ::: "memory");
        FENCE
        __builtin_amdgcn_s_barrier();
        if (++s >= 3) s -= 3;
    }
#undef FENCE

#pragma unroll
    for (int mi = 0; mi < 8; ++mi)
#pragma unroll
    for (int ni = 0; ni < 2; ++ni) {
        int row0 = m0 + wr * 128 + mi * 16 + lg * 4;
        int col  = n0 + wc * 32 + ni * 16 + l15;
#pragma unroll
        for (int r = 0; r < 4; ++r)
            C[(size_t)(row0 + r) * N + col] = acc[mi][ni][r];
    }
}

// ---------------- Fused RMSNorm+RoPE and V-transpose ----------------
__global__ __launch_bounds__(256) void nr_vt_kern(
    const u16* __restrict__ qkv, const float* __restrict__ qw,
    const float* __restrict__ kw, u16* __restrict__ qr, u16* __restrict__ kr,
    u16* __restrict__ vt)
{
    __shared__ u16 Ts[128][66];
    const int id = blockIdx.x, tid = threadIdx.x;
    if (id < 20480) {
        const int t = id & 2047, h = (id >> 11) * 4 + (tid >> 6);
        const int i = tid & 63;
        const size_t rowbase = (size_t)t * QKV_N;
        const u16* src; const float* w; u16* dst;
        if (h < 32) {
            src = qkv + rowbase + h * HD; w = qw;
            dst = qr + ((size_t)h * T_SEQ + t) * HD;
        } else {
            int kh = h - 32;
            src = qkv + rowbase + NQ * HD + kh * HD; w = kw;
            dst = kr + ((size_t)kh * T_SEQ + t) * HD;
        }
        float x1 = b2f(src[i]), x2 = b2f(src[i + 64]);
        float ss = x1 * x1 + x2 * x2;
#pragma unroll
        for (int d = 32; d >= 1; d >>= 1) ss += __shfl_xor(ss, d);
        float rs = rsqrtf(ss * (1.0f / 128.0f) + 1e-6f);
        x1 *= rs * w[i];
        x2 *= rs * w[i + 64];
        float ang = (float)t * exp2f((float)i * -0.20762050593567985f);
        float sn, cs;
        sincosf(ang, &sn, &cs);
        dst[i]      = f2bf(x1 * cs - x2 * sn);
        dst[i + 64] = f2bf(x2 * cs + x1 * sn);
        return;
    }
    const int id2 = id - 20480;
    const int t0 = (id2 & 31) * 64, kh = id2 >> 5;
#pragma unroll
    for (int it = 0; it < 4; ++it) {
        int slot = tid + it * 256;
        int tl = slot >> 4, dc = (slot & 15) * 8;
        s16x8 v = *(const s16x8*)&qkv[(size_t)(t0 + tl) * QKV_N + (NQ + NKV) * HD + kh * HD + dc];
#pragma unroll
        for (int e = 0; e < 8; ++e) Ts[dc + e][tl] = (u16)v[e];
    }
    __syncthreads();
#pragma unroll
    for (int it = 0; it < 4; ++it) {
        int slot = tid + it * 256;
        int d = slot >> 3, c = (slot & 7) * 8;
        s16x8 v = *(const s16x8*)&Ts[d][c];
        *(s16x8*)&vt[((size_t)kh * HD + d) * T_SEQ + t0 + c] = v;
    }
}

// ---------------- Flash attention (causal, GQA), swapped-QK^T, QBLK=128 --------
#define KS(b, r, c) Ks[(b)][((r) << 7) + ((c) ^ (((r) & 7) << 3))]
#define VS(b, r, c) Vs[(b)][((r) << 6) + ((c) ^ (((r) & 7) << 3))]
#define PS(wv, r, c) Ps[((wv) << 10) + ((r) << 6) + ((c) ^ (((r) & 7) << 3))]

__global__ __launch_bounds__(512) void attn_kern(
    const u16* __restrict__ qr, const u16* __restrict__ kr,
    const u16* __restrict__ vt, u16* __restrict__ o,
    const float* __restrict__ wo, u16* __restrict__ wo_bf)
{
    __shared__ u16 Ks[2][64 * 128];
    __shared__ u16 Vs[2][128 * 64];
    __shared__ u16 Ps[8 * 16 * 64];
    const int tid = threadIdx.x, lane = tid & 63, w = tid >> 6;
    const int lg = lane >> 4, l15 = lane & 15;
    const int fb = (int)blockIdx.y * 8 + (int)blockIdx.x;
    const int flat = xcd_swz(fb, 256);
    const int qh = flat >> 3, bx = flat & 7;
    const int kvh = qh >> 2;
    const float scale2 = 0.08838834764831845f * 1.4426950408889634f;

    const int cvbase = fb * 8192 + tid;
    int cv = 0;
    float4 cva = {}, cvb = {};

    const int krow = tid >> 4, kcol = (tid & 15) * 8;
    const int vrow = tid >> 3, vcol = (tid & 7) * 8;
    const u16* krbase = kr + (size_t)kvh * T_SEQ * HD;
    const u16* vtbase = vt + (size_t)kvh * HD * T_SEQ;

    s16x8 kst[2], vst[2];
#define LOADKV(k0_) do { \
    kst[0] = *(const s16x8*)&krbase[(size_t)((k0_) + krow) * HD + kcol]; \
    kst[1] = *(const s16x8*)&krbase[(size_t)((k0_) + krow + 32) * HD + kcol]; \
    vst[0] = *(const s16x8*)&vtbase[(size_t)(vrow) * T_SEQ + (k0_) + vcol]; \
    vst[1] = *(const s16x8*)&vtbase[(size_t)(vrow + 64) * T_SEQ + (k0_) + vcol]; \
    } while (0)
#define WRITEKV(b) do { \
    *(s16x8*)&KS((b), krow, kcol) = kst[0]; \
    *(s16x8*)&KS((b), krow + 32, kcol) = kst[1]; \
    *(s16x8*)&VS((b), vrow, vcol) = vst[0]; \
    *(s16x8*)&VS((b), vrow + 64, vcol) = vst[1]; \
    } while (0)

    for (int half = 0; half < 2; ++half) {
        const int q0 = (half == 0) ? bx * 128 : (T_SEQ - 128) - bx * 128;
        s16x8 qf[4];
        {
            const u16* qb = qr + ((size_t)qh * T_SEQ + q0 + w * 16 + l15) * HD;
#pragma unroll
            for (int dc = 0; dc < 4; ++dc) qf[dc] = *(const s16x8*)&qb[dc * 32 + lg * 8];
        }
        f32x4 oacc[8] = {};
        float mQ = -1e30f, lsQ = 0.f;

        const int ktiles = (q0 >> 6) + 2;
        LOADKV(0);
        WRITEKV(0);
        __syncthreads();
        for (int kt = 0; kt < ktiles; ++kt) {
            const int k0 = kt * 64;
            const int cur = kt & 1;
            if (kt + 1 < ktiles) LOADKV(k0 + 64);

            if (cv <= 16) {
                if (cv > 0) {
                    s16x8 o8;
                    o8[0] = (short)f2bf(cva.x); o8[1] = (short)f2bf(cva.y);
                    o8[2] = (short)f2bf(cva.z); o8[3] = (short)f2bf(cva.w);
                    o8[4] = (short)f2bf(cvb.x); o8[5] = (short)f2bf(cvb.y);
                    o8[6] = (short)f2bf(cvb.z); o8[7] = (short)f2bf(cvb.w);
                    ((s16x8*)wo_bf)[cvbase + (cv - 1) * 512] = o8;
                }
                if (cv < 16) {
                    cva = ((const float4*)wo)[2 * (cvbase + cv * 512)];
                    cvb = ((const float4*)wo)[2 * (cvbase + cv * 512) + 1];
                }
                ++cv;
            }

            f32x4 sc[4] = {};
            __builtin_amdgcn_s_setprio(1);
#pragma unroll
            for (int nc = 0; nc < 4; ++nc)
#pragma unroll
                for (int dc = 0; dc < 4; ++dc) {
                    s16x8 kf = *(const s16x8*)&KS(cur, nc * 16 + l15, dc * 32 + lg * 8);
                    sc[nc] = __builtin_amdgcn_mfma_f32_16x16x32_bf16(kf, qf[dc], sc[nc], 0, 0, 0);
                }
            __builtin_amdgcn_s_setprio(0);

            const int qg = q0 + w * 16 + l15;
            const bool needMask = (k0 + 63) > (q0 + w * 16);
            float tm = -1e30f;
#pragma unroll
            for (int nc = 0; nc < 4; ++nc)
#pragma unroll
                for (int r = 0; r < 4; ++r) {
                    float v = sc[nc][r] * scale2;
                    int kg = k0 + nc * 16 + lg * 4 + r;
                    if (needMask && kg > qg) v = -1e30f;
                    sc[nc][r] = v;
                    tm = fmaxf(tm, v);
                }
            tm = fmaxf(tm, __shfl_xor(tm, 16));
            tm = fmaxf(tm, __shfl_xor(tm, 32));

            if (__any(tm > mQ + 8.0f)) {
                float mn = fmaxf(mQ, tm);
                float alpha = exp2f(mQ - mn);
                mQ = mn;
                lsQ *= alpha;
                float aq[4];
#pragma unroll
                for (int r = 0; r < 4; ++r) aq[r] = __shfl(alpha, lg * 4 + r);
#pragma unroll
                for (int dc = 0; dc < 8; ++dc)
#pragma unroll
                    for (int r = 0; r < 4; ++r) oacc[dc][r] *= aq[r];
            }

            float ts = 0.f;
#pragma unroll
            for (int nc = 0; nc < 4; ++nc) {
                s16x4 pk;
#pragma unroll
                for (int r = 0; r < 4; ++r) {
                    float e = exp2f(sc[nc][r] - mQ);
                    ts += e;
                    pk[r] = (short)f2bf(e);
                }
                *(s16x4*)&PS(w, l15, nc * 16 + lg * 4) = pk;
            }
            ts += __shfl_xor(ts, 16);
            ts += __shfl_xor(ts, 32);
            lsQ += ts;

            __builtin_amdgcn_s_setprio(1);
#pragma unroll
            for (int kc = 0; kc < 2; ++kc) {
                s16x8 pf = *(const s16x8*)&PS(w, l15, kc * 32 + lg * 8);
#pragma unroll
                for (int dc = 0; dc < 8; ++dc) {
                    s16x8 vf = *(const s16x8*)&VS(cur, dc * 16 + l15, kc * 32 + lg * 8);
                    oacc[dc] = __builtin_amdgcn_mfma_f32_16x16x32_bf16(pf, vf, oacc[dc], 0, 0, 0);
                }
            }
            __builtin_amdgcn_s_setprio(0);

            if (kt + 1 < ktiles) WRITEKV(cur ^ 1);
            __syncthreads();
        }
        float lq[4];
#pragma unroll
        for (int r = 0; r < 4; ++r) lq[r] = __shfl(lsQ, lg * 4 + r);
#pragma unroll
        for (int r = 0; r < 4; ++r) {
            float inv = 1.0f / lq[r];
            int trow = q0 + w * 16 + lg * 4 + r;
            u16* dst = o + (size_t)trow * (NQ * HD) + qh * HD;
#pragma unroll
            for (int dc = 0; dc < 8; ++dc) dst[dc * 16 + l15] = f2bf(oacc[dc][r] * inv);
        }
    }
#undef LOADKV
#undef WRITEKV
}

extern "C" void kernel_launch(void* const* d_in, const int* in_sizes, int n_in,
                              void* d_out, int out_size, void* d_ws, size_t ws_size,
                              hipStream_t stream)
{
    const float* hs   = (const float*)d_in[0];
    const float* wqkv = (const float*)d_in[1];
    const float* qw   = (const float*)d_in[2];
    const float* kw   = (const float*)d_in[3];
    const float* wo   = (const float*)d_in[4];
    float* out = (float*)d_out;

    // workspace 92,274,688 B (88 MiB). Fully disjoint live regions per stage:
    //   gemm1: R hs_bf[0,16M) + wqkv_bf[40,88M)  -> W qkv_bf[16,40M)
    //   nr_vt: R qkv_bf[16,40M)                  -> W qr[64,80M) kr[80,84M) vt[84,88M)
    //   attn : R qr/kr/vt[64,88M) + wo(input)    -> W ob[0,16M) + wo_bf[16,48M)
    //   gemm2: R ob[0,16M) + wo_bf[16,48M)       -> W d_out
    char* ws = (char*)d_ws;
    u16* hs_bf   = (u16*)(ws);                  // [0,16M)
    u16* ob      = (u16*)(ws);                  // [0,16M)  (after gemm1)
    u16* qkv_bf  = (u16*)(ws + 16777216);       // [16,40M)
    u16* wo_bf   = (u16*)(ws + 16777216);       // [16,48M) (after nr_vt)
    u16* wqkv_bf = (u16*)(ws + 41943040);       // [40,88M)
    u16* qr      = (u16*)(ws + 67108864);       // [64,80M)
    u16* kr      = (u16*)(ws + 83886080);       // [80,84M)
    u16* vt      = (u16*)(ws + 88080384);       // [84,88M)

    // 1) convert hs + wqkv
    conv2_bf16_kern<<<2048, 256, 0, stream>>>(
        hs, hs_bf, T_SEQ * HIDDEN / 8, wqkv, wqkv_bf, QKV_N * HIDDEN / 8);
    // 2) qkv = hs @ wqkv^T  (256x192 2-sync mixed-slot, 256 blocks = 1/CU)
    gemm1_2ph<<<dim3(QKV_N / 192, T_SEQ / 256), 512, 0, stream>>>(
        hs_bf, wqkv_bf, qkv_bf, QKV_N, HIDDEN);
    // 3) fused norm+rope / V-transpose (last reader of qkv_bf)
    nr_vt_kern<<<20736, 256, 0, stream>>>(qkv_bf, qw, kw, qr, kr, vt);
    // 4) attention with embedded wo conversion
    attn_kern<<<dim3(8, NQ), 512, 0, stream>>>(qr, kr, vt, ob, wo, wo_bf);
    // 5) out = o @ wo^T  (256x128 2-sync 3-slot, 256 blocks = 1/CU)
    gemm2_2ph<<<dim3(HIDDEN / 128, T_SEQ / 256), 512, 0, stream>>>(
        ob, wo_bf, out, HIDDEN, HIDDEN);
}